// Round 14
// baseline (172.942 us; speedup 1.0000x reference)
//
#include <hip/hip_runtime.h>

typedef __attribute__((ext_vector_type(8))) short bf16x8;
typedef __attribute__((ext_vector_type(4))) short bf16x4;
typedef __attribute__((ext_vector_type(4))) float f32x4;
typedef unsigned short u16;

constexpr int B_   = 16;
constexpr int C_   = 256;
constexpr int NH   = 8;
constexpr int DH   = 64;
constexpr int NMEM = 4;
constexpr int HID  = 512;    // NH*DH
constexpr int QKVC = 1536;   // 3*HID
constexpr int N_   = 4096;   // 64*64
constexpr int CTXS = 4224;   // per-nc ctxp stride: 4096 ctx + 128 rsum slots

__device__ __forceinline__ u16 f2b(float f) {   // RNE f32->bf16
  union { float f; unsigned u; } v{f};
  unsigned r = v.u + 0x7fff + ((v.u >> 16) & 1);
  return (u16)(r >> 16);
}
__device__ __forceinline__ float b2f(u16 h) {
  union { unsigned u; float f; } v; v.u = ((unsigned)h) << 16; return v.f;
}

// async global->LDS, 16B per lane; lds dest = wave-uniform base + lane*16B
__device__ __forceinline__ void gld_lds16(const u16* g, u16* l) {
  __builtin_amdgcn_global_load_lds(
      (const __attribute__((address_space(1))) unsigned*)g,
      (__attribute__((address_space(3))) unsigned*)l, 16, 0, 0);
}

// ---------------- weights -> bf16 (once per call) ----------------
__global__ void k_cvtw(const float* __restrict__ wq, const float* __restrict__ wo,
                       u16* __restrict__ wqb, u16* __restrict__ wob) {
  int i = blockIdx.x * 256 + threadIdx.x;
  for (int idx = i; idx < QKVC * C_; idx += gridDim.x * 256) wqb[idx] = f2b(wq[idx]);
  for (int idx = i; idx < C_ * HID; idx += gridDim.x * 256) wob[idx] = f2b(wo[idx]);
}

// ---------------- rmsnorm1 + transpose to bf16 [g][n][c] ----------------
__global__ __launch_bounds__(256) void k_rms1(const float* __restrict__ x,
                                              const float* __restrict__ g1,
                                              u16* __restrict__ xbT) {
  int g = blockIdx.y;
  int n = blockIdx.x * 64 + (threadIdx.x & 63);
  int ch = threadIdx.x >> 6;                   // c-quarter 0..3
  __shared__ float ssp[4][64];
  __shared__ float invs[64];
  const float* xp = x + (size_t)g * C_ * N_ + n;
  float ss = 0.f;
  #pragma unroll 16
  for (int c = ch * 64; c < ch * 64 + 64; ++c) {
    float v = xp[(size_t)c * N_];
    ss += v * v;
  }
  ssp[ch][n & 63] = ss;
  __syncthreads();
  if (threadIdx.x < 64) {
    float tot = (ssp[0][threadIdx.x] + ssp[1][threadIdx.x]) +
                (ssp[2][threadIdx.x] + ssp[3][threadIdx.x]);
    invs[threadIdx.x] = 16.0f / fmaxf(sqrtf(tot), 1e-12f);
  }
  __syncthreads();
  float inv = invs[n & 63];
  u16* op = xbT + ((size_t)g * N_ + n) * C_;
  #pragma unroll 2
  for (int c0 = ch * 64; c0 < ch * 64 + 64; c0 += 8) {
    union { bf16x8 v; u16 u[8]; } pk;
    #pragma unroll
    for (int j = 0; j < 8; ++j) pk.u[j] = f2b(xp[(size_t)(c0 + j) * N_] * inv * g1[c0 + j]);
    *(bf16x8*)(op + c0) = pk.v;
  }
}

// ---------------- fused KV-GEMM + exp + PV-accumulate, BK=64 ----------------
__global__ __launch_bounds__(256) void k_kvctx(const u16* __restrict__ Wb,
                                               const u16* __restrict__ XT,
                                               float* __restrict__ ctxp) {
  __shared__ __align__(16) u16 smem[16384];    // 32 KB
  u16* Ws = smem;
  u16* Xs = smem + 8192;
  u16* Pl = smem;
  u16* Vl = smem + 8192;

  int cpx = gridDim.x >> 3;                    // nwg = 64*G, %8==0
  int bid = blockIdx.x;
  int L = (bid & 7) * cpx + (bid >> 3);
  int h = L & 7, nc = (L >> 3) & 7, g = L >> 6;
  int t = threadIdx.x, wave = t >> 6, lane = t & 63;
  int wm = wave >> 1, wn = wave & 1;
  int kg = lane >> 4, lr = lane & 15;

  const u16* WK = Wb + (size_t)(HID + h * DH) * C_;
  const u16* WV = Wb + (size_t)(2 * HID + h * DH) * C_;
  const u16* Xg = XT + ((size_t)g * N_ + nc * 512) * C_;

  int rl8 = lane >> 3;
  int cs8 = (lane & 7) ^ rl8;
  const u16* Wsrc = (wave < 2) ? WK : WV;

  f32x4 acc2[4];
  #pragma unroll
  for (int nf = 0; nf < 4; ++nf) acc2[nf] = (f32x4)0.f;
  float rs[4] = {0.f, 0.f, 0.f, 0.f};

  for (int it = 0; it < 4; ++it) {
    f32x4 acc[4][4];
    #pragma unroll
    for (int i = 0; i < 4; ++i)
      #pragma unroll
      for (int j = 0; j < 4; ++j) acc[i][j] = (f32x4)0.f;

    for (int k0 = 0; k0 < C_; k0 += 64) {
      #pragma unroll
      for (int q = 0; q < 4; ++q) {
        int rb = wave * 32 + q * 8;
        int rw = (rb & 63) + rl8;
        int rx = it * 128 + rb + rl8;
        gld_lds16(Wsrc + (size_t)rw * C_ + k0 + cs8 * 8, Ws + rb * 64);
        gld_lds16(Xg + (size_t)rx * C_ + k0 + cs8 * 8, Xs + rb * 64);
      }
      __syncthreads();
      #pragma unroll
      for (int ks = 0; ks < 2; ++ks) {
        int ch = ks * 4 + kg;
        bf16x8 a[4], bv[4];
        #pragma unroll
        for (int mf = 0; mf < 4; ++mf) {
          int r = wm * 64 + mf * 16 + lr;
          a[mf] = *(const bf16x8*)(Xs + r * 64 + ((ch ^ (r & 7)) * 8));
        }
        #pragma unroll
        for (int nf = 0; nf < 4; ++nf) {
          int r = wn * 64 + nf * 16 + lr;
          bv[nf] = *(const bf16x8*)(Ws + r * 64 + ((ch ^ (r & 7)) * 8));
        }
        #pragma unroll
        for (int mf = 0; mf < 4; ++mf)
          #pragma unroll
          for (int nf = 0; nf < 4; ++nf)
            acc[mf][nf] = __builtin_amdgcn_mfma_f32_16x16x32_bf16(a[mf], bv[nf], acc[mf][nf], 0, 0, 0);
      }
      __syncthreads();
    }

    if (wn == 0) {
      #pragma unroll
      for (int mf = 0; mf < 4; ++mf) {
        int nb = wm * 64 + mf * 16 + kg * 4;
        int cc = nb >> 3, off = nb & 7;
        #pragma unroll
        for (int nf = 0; nf < 4; ++nf) {
          int d = nf * 16 + lr;
          float e0 = __expf(acc[mf][nf][0]);
          float e1 = __expf(acc[mf][nf][1]);
          float e2 = __expf(acc[mf][nf][2]);
          float e3 = __expf(acc[mf][nf][3]);
          rs[nf] += (e0 + e1) + (e2 + e3);
          union { bf16x4 v; u16 u[4]; } pk;
          pk.u[0] = f2b(e0); pk.u[1] = f2b(e1); pk.u[2] = f2b(e2); pk.u[3] = f2b(e3);
          *(bf16x4*)(Pl + d * 128 + ((cc ^ (d & 15)) * 8) + off) = pk.v;
        }
      }
    } else {
      #pragma unroll
      for (int mf = 0; mf < 4; ++mf) {
        int nb = wm * 64 + mf * 16 + kg * 4;
        int cc = nb >> 3, off = nb & 7;
        #pragma unroll
        for (int nf = 0; nf < 4; ++nf) {
          int e = nf * 16 + lr;
          union { bf16x4 v; u16 u[4]; } pk;
          pk.u[0] = f2b(acc[mf][nf][0]); pk.u[1] = f2b(acc[mf][nf][1]);
          pk.u[2] = f2b(acc[mf][nf][2]); pk.u[3] = f2b(acc[mf][nf][3]);
          *(bf16x4*)(Vl + e * 128 + ((cc ^ (e & 15)) * 8) + off) = pk.v;
        }
      }
    }
    __syncthreads();

    #pragma unroll
    for (int k = 0; k < 4; ++k) {
      int c = k * 4 + kg;
      bf16x8 af = *(const bf16x8*)(Pl + (wave * 16 + lr) * 128 + ((c ^ lr) * 8));
      #pragma unroll
      for (int nf = 0; nf < 4; ++nf) {
        bf16x8 bfv = *(const bf16x8*)(Vl + (nf * 16 + lr) * 128 + ((c ^ lr) * 8));
        acc2[nf] = __builtin_amdgcn_mfma_f32_16x16x32_bf16(af, bfv, acc2[nf], 0, 0, 0);
      }
    }
    __syncthreads();
  }

  float* cgp = ctxp + ((size_t)(g * NH + h) * 8 + nc) * CTXS;
  #pragma unroll
  for (int nf = 0; nf < 4; ++nf)
    #pragma unroll
    for (int j = 0; j < 4; ++j) {
      int d = wave * 16 + kg * 4 + j;
      int e = nf * 16 + lr;
      cgp[d * 64 + e] = acc2[nf][j];
    }
  if (wn == 0) {
    #pragma unroll
    for (int nf = 0; nf < 4; ++nf) {
      rs[nf] += __shfl_xor(rs[nf], 16);
      rs[nf] += __shfl_xor(rs[nf], 32);
    }
    if (lane < 16) {
      #pragma unroll
      for (int nf = 0; nf < 4; ++nf)
        cgp[4096 + wm * 64 + nf * 16 + lane] = rs[nf];
    }
  }
}

// ---------------- ctx finalize + Wo2 = Wo_h @ ctx_h^T : wo2[g][c][h*64+d] bf16 ----------------
__global__ __launch_bounds__(256) void k_cwo(const float* __restrict__ ctxp,
                                             const float* __restrict__ memkv,
                                             const u16* __restrict__ Wo,
                                             u16* __restrict__ wo2) {
  int g = blockIdx.y, h = blockIdx.x;
  int t = threadIdx.x, wave = t >> 6, lane = t & 63;
  int kg = lane >> 4, lr = lane & 15;
  int rl8 = lane >> 3, cs8 = (lane & 7) ^ rl8;
  __shared__ float emk[DH * NMEM];
  __shared__ float sd[DH];
  __shared__ __align__(16) u16 Cl[64 * 64];    // ctx[d][e] bf16, swizzled (8 KB)
  __shared__ __align__(16) u16 As2[256 * 64];  // Wo slice rows c x 64 e (32 KB)

  const float* mk = memkv + (size_t)h * DH * NMEM;
  const float* mv = memkv + (size_t)(NH + h) * DH * NMEM;
  const float* cp = ctxp + (size_t)(g * NH + h) * 8 * CTXS;
  emk[t] = __expf(mk[t]);
  __syncthreads();
  if (t < DH) {
    float s = 0.f;
    #pragma unroll
    for (int p = 0; p < 8; ++p)
      s += cp[p * CTXS + 4096 + t] + cp[p * CTXS + 4160 + t];
    #pragma unroll
    for (int j = 0; j < NMEM; ++j) s += emk[t * 4 + j];
    sd[t] = s;
  }
  #pragma unroll
  for (int q = 0; q < 8; ++q) {
    int rb = wave * 64 + q * 8;
    gld_lds16(Wo + (size_t)(rb + rl8) * HID + h * DH + cs8 * 8, As2 + rb * 64);
  }
  __syncthreads();
  #pragma unroll
  for (int i = 0; i < 16; ++i) {
    int idx = t + 256 * i;
    int d = idx >> 6, e = idx & 63;
    float v = 0.f;
    #pragma unroll
    for (int p = 0; p < 8; ++p) v += cp[p * CTXS + idx];
    #pragma unroll
    for (int j = 0; j < NMEM; ++j) v += emk[d * 4 + j] * mv[e * 4 + j];
    Cl[d * 64 + (((e >> 3) ^ (d & 7)) * 8) + (e & 7)] = f2b(v / sd[d]);
  }
  __syncthreads();
  f32x4 acc[4][4];
  #pragma unroll
  for (int i = 0; i < 4; ++i)
    #pragma unroll
    for (int j = 0; j < 4; ++j) acc[i][j] = (f32x4)0.f;
  #pragma unroll
  for (int ks = 0; ks < 2; ++ks) {
    int ch = ks * 4 + kg;
    bf16x8 a[4], b[4];
    #pragma unroll
    for (int mf = 0; mf < 4; ++mf) {
      int r = wave * 64 + mf * 16 + lr;
      a[mf] = *(const bf16x8*)(As2 + r * 64 + ((ch ^ (r & 7)) * 8));
    }
    #pragma unroll
    for (int nf = 0; nf < 4; ++nf) {
      int rd = nf * 16 + lr;
      b[nf] = *(const bf16x8*)(Cl + rd * 64 + ((ch ^ (rd & 7)) * 8));
    }
    #pragma unroll
    for (int mf = 0; mf < 4; ++mf)
      #pragma unroll
      for (int nf = 0; nf < 4; ++nf)
        acc[mf][nf] = __builtin_amdgcn_mfma_f32_16x16x32_bf16(a[mf], b[nf], acc[mf][nf], 0, 0, 0);
  }
  u16* og = wo2 + (size_t)g * 256 * 512;
  #pragma unroll
  for (int mf = 0; mf < 4; ++mf)
    #pragma unroll
    for (int nf = 0; nf < 4; ++nf)
      #pragma unroll
      for (int j = 0; j < 4; ++j) {
        int c = wave * 64 + mf * 16 + kg * 4 + j;
        int dd = nf * 16 + lr;
        og[(size_t)c * 512 + h * DH + dd] = f2b(acc[mf][nf][j]);
      }
}

// ---------------- fused Q-GEMM + q-softmax + out-proj + rmsnorm2, BN=128 ----------------
// block: 512 threads, 128-n tile. Phase A: Q (512o x 128n, K=256), wave w = head w.
// Phase B: per-head softmax (wave-local), qsm -> swizzled LDS in two 256-o halves.
// Phase C: out (256c x 128n, K=512 over Wo2), bias + rmsnorm over c, f32 store.
__global__ __launch_bounds__(512, 2) void k_qout(const u16* __restrict__ Wq,
                                                 const u16* __restrict__ XT,
                                                 const u16* __restrict__ Wo2,
                                                 const float* __restrict__ bias,
                                                 const float* __restrict__ g2,
                                                 float* __restrict__ out) {
  __shared__ __align__(16) u16 smem[49152];    // 96 KB
  u16* R0 = smem;            // 32 KB: Wq-stage (512x32) / Wo2-stage (256x64) / part
  u16* R1 = smem + 16384;    // 64 KB: X-tile [128 n][256 c] / Ql half [128 n][256 o]

  int cpx = gridDim.x >> 3;                    // nwg = 32*G, %8==0
  int bid = blockIdx.x;
  int L = (bid & 7) * cpx + (bid >> 3);
  int nc = L & 31, g = L >> 5;
  int t = threadIdx.x, wave = t >> 6, lane = t & 63;
  int kg = lane >> 4, lr = lane & 15;
  int rl4 = lane >> 2, cs4 = (lane & 3) ^ (rl4 & 3);   // 4-chunk rows (64B)
  int rl8 = lane >> 3, cs8 = (lane & 7) ^ rl8;         // 8-chunk rows (128B)

  const u16* Xg = XT + ((size_t)g * N_ + nc * 128) * C_;
  const u16* W2g = Wo2 + (size_t)g * 256 * 512;

  // stage X tile once: [128 n][256 c], low-3-chunk swizzle by n&7
  {
    int xrow_off = lane >> 5;                  // 0..1
    int c32 = lane & 31;
    #pragma unroll
    for (int q = 0; q < 8; ++q) {
      int base = wave * 16 + q * 2;
      int row = base + xrow_off;
      int sw = (c32 & 24) | ((c32 & 7) ^ (row & 7));
      gld_lds16(Xg + (size_t)row * C_ + sw * 8, R1 + base * 256);
    }
  }

  // ---- phase A: Q-GEMM, BK=32, 8 steps, acc 64o x 128n per wave ----
  f32x4 acc[4][8];
  #pragma unroll
  for (int i = 0; i < 4; ++i)
    #pragma unroll
    for (int j = 0; j < 8; ++j) acc[i][j] = (f32x4)0.f;

  for (int k0i = 0; k0i < 8; ++k0i) {
    int k0 = k0i * 32;
    #pragma unroll
    for (int q = 0; q < 4; ++q) {              // Wq slice 512 rows x 32
      int rb = ((wave * 4 + q) & 31) * 16;
      gld_lds16(Wq + (size_t)(rb + rl4) * C_ + k0 + cs4 * 8, R0 + rb * 32);
    }
    __syncthreads();
    bf16x8 a[4], bv[8];
    #pragma unroll
    for (int mf = 0; mf < 4; ++mf) {           // A = Wq rows (o)
      int r = wave * 64 + mf * 16 + lr;
      a[mf] = *(const bf16x8*)(R0 + r * 32 + ((kg ^ (r & 3)) * 8));
    }
    #pragma unroll
    for (int nf = 0; nf < 8; ++nf) {           // B = X rows (n)
      int bn = nf * 16 + lr;
      int c32 = k0i * 4 + kg;
      int sw = (c32 & 24) | ((c32 & 7) ^ (bn & 7));
      bv[nf] = *(const bf16x8*)(R1 + bn * 256 + sw * 8);
    }
    #pragma unroll
    for (int mf = 0; mf < 4; ++mf)
      #pragma unroll
      for (int nf = 0; nf < 8; ++nf)
        acc[mf][nf] = __builtin_amdgcn_mfma_f32_16x16x32_bf16(a[mf], bv[nf], acc[mf][nf], 0, 0, 0);
    __syncthreads();
  }

  // ---- phase B: per-head softmax (head = wave), scale ----
  float colsum[8];
  #pragma unroll
  for (int nf = 0; nf < 8; ++nf) {
    float s = 0.f;
    #pragma unroll
    for (int mf = 0; mf < 4; ++mf)
      #pragma unroll
      for (int j = 0; j < 4; ++j) {
        float e = __expf(acc[mf][nf][j]);
        acc[mf][nf][j] = e;
        s += e;
      }
    colsum[nf] = s;
  }
  #pragma unroll
  for (int nf = 0; nf < 8; ++nf) {
    colsum[nf] += __shfl_xor(colsum[nf], 16);
    colsum[nf] += __shfl_xor(colsum[nf], 32);
    colsum[nf] = 0.125f / colsum[nf];
  }

  f32x4 acc2[2][8];
  #pragma unroll
  for (int i = 0; i < 2; ++i)
    #pragma unroll
    for (int j = 0; j < 8; ++j) acc2[i][j] = (f32x4)0.f;

  #pragma unroll
  for (int half = 0; half < 2; ++half) {
    if ((wave >> 2) == half) {
      #pragma unroll
      for (int nf = 0; nf < 8; ++nf) {
        int n = nf * 16 + lr;
        float invs = colsum[nf];
        #pragma unroll
        for (int mf = 0; mf < 4; ++mf)
          #pragma unroll
          for (int jp = 0; jp < 2; ++jp) {
            int oc = (wave & 3) * 64 + mf * 16 + kg * 4 + jp * 2;
            u16 lo = f2b(acc[mf][nf][jp * 2] * invs);
            u16 hi = f2b(acc[mf][nf][jp * 2 + 1] * invs);
            unsigned pk = (unsigned)lo | ((unsigned)hi << 16);
            int c8 = oc >> 3;
            int sw = (c8 & 24) | ((c8 & 7) ^ (n & 7));
            *(unsigned*)(R1 + n * 256 + sw * 8 + (oc & 7)) = pk;
          }
      }
    }
    __syncthreads();
    // ---- phase C (this K-half): out-GEMM, 4 k0-steps of 64 ----
    for (int k0l = 0; k0l < 4; ++k0l) {
      int cb = half * 256 + k0l * 64;
      #pragma unroll
      for (int q = 0; q < 4; ++q) {            // Wo2 slice 256 rows x 64
        int rb = ((wave * 4 + q) & 31) * 8;
        gld_lds16(W2g + (size_t)(rb + rl8) * 512 + cb + cs8 * 8, R0 + rb * 64);
      }
      __syncthreads();
      #pragma unroll
      for (int ks = 0; ks < 2; ++ks) {
        int ch = ks * 4 + kg;
        bf16x8 a2[2], b2[8];
        #pragma unroll
        for (int mf = 0; mf < 2; ++mf) {       // A = Wo2 rows (c), 32 per wave
          int r = wave * 32 + mf * 16 + lr;
          a2[mf] = *(const bf16x8*)(R0 + r * 64 + ((ch ^ (r & 7)) * 8));
        }
        #pragma unroll
        for (int nf = 0; nf < 8; ++nf) {       // B = Ql rows (n)
          int bn = nf * 16 + lr;
          int c8 = k0l * 8 + ks * 4 + kg;
          int sw = (c8 & 24) | ((c8 & 7) ^ (bn & 7));
          b2[nf] = *(const bf16x8*)(R1 + bn * 256 + sw * 8);
        }
        #pragma unroll
        for (int mf = 0; mf < 2; ++mf)
          #pragma unroll
          for (int nf = 0; nf < 8; ++nf)
            acc2[mf][nf] = __builtin_amdgcn_mfma_f32_16x16x32_bf16(a2[mf], b2[nf], acc2[mf][nf], 0, 0, 0);
      }
      __syncthreads();
    }
  }

  // ---- epilogue: bias + rmsnorm over c (256 rows) + store ----
  float colsq[8] = {0.f, 0.f, 0.f, 0.f, 0.f, 0.f, 0.f, 0.f};
  #pragma unroll
  for (int mf = 0; mf < 2; ++mf)
    #pragma unroll
    for (int j = 0; j < 4; ++j) {
      int c = wave * 32 + mf * 16 + kg * 4 + j;
      float bs = bias[c];
      #pragma unroll
      for (int nf = 0; nf < 8; ++nf) {
        float v = acc2[mf][nf][j] + bs;
        acc2[mf][nf][j] = v;
        colsq[nf] += v * v;
      }
    }
  #pragma unroll
  for (int nf = 0; nf < 8; ++nf) {
    colsq[nf] += __shfl_xor(colsq[nf], 16);
    colsq[nf] += __shfl_xor(colsq[nf], 32);
  }
  float* part = (float*)R0;                    // 8 x 128 f32 = 4 KB
  if (kg == 0) {
    #pragma unroll
    for (int nf = 0; nf < 8; ++nf) part[wave * 128 + nf * 16 + lr] = colsq[nf];
  }
  __syncthreads();
  float* og = out + (size_t)g * C_ * N_ + nc * 128;
  #pragma unroll
  for (int nf = 0; nf < 8; ++nf) {
    int col = nf * 16 + lr;
    float tot = 0.f;
    #pragma unroll
    for (int w = 0; w < 8; ++w) tot += part[w * 128 + col];
    float invn = 16.0f / fmaxf(sqrtf(tot), 1e-12f);
    #pragma unroll
    for (int mf = 0; mf < 2; ++mf)
      #pragma unroll
      for (int j = 0; j < 4; ++j) {
        int c = wave * 32 + mf * 16 + kg * 4 + j;
        og[(size_t)c * N_ + col] = acc2[mf][nf][j] * invn * g2[c];
      }
  }
}

extern "C" void kernel_launch(void* const* d_in, const int* in_sizes, int n_in,
                              void* d_out, int out_size, void* d_ws, size_t ws_size,
                              hipStream_t stream) {
  (void)in_sizes; (void)n_in; (void)out_size;
  const float* x      = (const float*)d_in[0];
  const float* gain1  = (const float*)d_in[1];
  const float* w_qkv  = (const float*)d_in[2];
  const float* mem_kv = (const float*)d_in[3];
  const float* w_out  = (const float*)d_in[4];
  const float* b_out  = (const float*)d_in[5];
  const float* gain2  = (const float*)d_in[6];
  float* out = (float*)d_out;

  char* ws = (char*)d_ws;
  u16* wqkvb = (u16*)ws;                         // 786,432 B
  u16* woutb = (u16*)(ws + 786432);              // 262,144 B
  size_t shared_b = 1048576;

  const size_t xbT_b  = (size_t)N_ * C_ * 2;           //  2 MiB
  const size_t ctxp_b = (size_t)NH * 8 * CTXS * 4;     // ~1.03 MiB
  const size_t wo2_b  = (size_t)256 * 512 * 2;         // 256 KiB
  const size_t per_b  = xbT_b + ctxp_b + wo2_b;

  int G = 16;
  while (G > 1 && shared_b + (size_t)G * per_b > ws_size) G >>= 1;

  char* base = ws + shared_b;
  u16*   xbT  = (u16*)base;
  float* ctxp = (float*)(base + (size_t)G * xbT_b);
  u16*   wo2  = (u16*)(base + (size_t)G * (xbT_b + ctxp_b));

  k_cvtw<<<256, 256, 0, stream>>>(w_qkv, w_out, wqkvb, woutb);

  for (int b0 = 0; b0 < B_; b0 += G) {
    const float* xc = x + (size_t)b0 * C_ * N_;
    float*       oc = out + (size_t)b0 * C_ * N_;
    k_rms1  <<<dim3(N_ / 64, G),   256, 0, stream>>>(xc, gain1, xbT);
    k_kvctx <<<dim3(64 * G),       256, 0, stream>>>(wqkvb, xbT, ctxp);
    k_cwo   <<<dim3(NH, G),        256, 0, stream>>>(ctxp, mem_kv, woutb, wo2);
    k_qout  <<<dim3(32 * G),       512, 0, stream>>>(wqkvb, xbT, wo2, b_out, gain2, oc);
  }
}

// Round 15
// 164.707 us; speedup vs baseline: 1.0500x; 1.0500x over previous
//
#include <hip/hip_runtime.h>

typedef __attribute__((ext_vector_type(8))) short bf16x8;
typedef __attribute__((ext_vector_type(4))) short bf16x4;
typedef __attribute__((ext_vector_type(4))) float f32x4;
typedef unsigned short u16;

constexpr int B_   = 16;
constexpr int C_   = 256;
constexpr int NH   = 8;
constexpr int DH   = 64;
constexpr int NMEM = 4;
constexpr int HID  = 512;    // NH*DH
constexpr int QKVC = 1536;   // 3*HID
constexpr int N_   = 4096;   // 64*64
constexpr int CTXS = 4224;   // per-nc ctxp stride: 4096 ctx + 128 rsum slots

__device__ __forceinline__ u16 f2b(float f) {   // RNE f32->bf16
  union { float f; unsigned u; } v{f};
  unsigned r = v.u + 0x7fff + ((v.u >> 16) & 1);
  return (u16)(r >> 16);
}
__device__ __forceinline__ float b2f(u16 h) {
  union { unsigned u; float f; } v; v.u = ((unsigned)h) << 16; return v.f;
}

// async global->LDS, 16B per lane; lds dest = wave-uniform base + lane*16B
__device__ __forceinline__ void gld_lds16(const u16* g, u16* l) {
  __builtin_amdgcn_global_load_lds(
      (const __attribute__((address_space(1))) unsigned*)g,
      (__attribute__((address_space(3))) unsigned*)l, 16, 0, 0);
}

// ---------------- weights -> bf16 (once per call) ----------------
__global__ void k_cvtw(const float* __restrict__ wq, const float* __restrict__ wo,
                       u16* __restrict__ wqb, u16* __restrict__ wob) {
  int i = blockIdx.x * 256 + threadIdx.x;
  for (int idx = i; idx < QKVC * C_; idx += gridDim.x * 256) wqb[idx] = f2b(wq[idx]);
  for (int idx = i; idx < C_ * HID; idx += gridDim.x * 256) wob[idx] = f2b(wo[idx]);
}

// ---------------- rmsnorm1 + transpose to bf16 [g][n][c] ----------------
__global__ __launch_bounds__(256) void k_rms1(const float* __restrict__ x,
                                              const float* __restrict__ g1,
                                              u16* __restrict__ xbT) {
  int g = blockIdx.y;
  int n = blockIdx.x * 64 + (threadIdx.x & 63);
  int ch = threadIdx.x >> 6;                   // c-quarter 0..3
  __shared__ float ssp[4][64];
  __shared__ float invs[64];
  const float* xp = x + (size_t)g * C_ * N_ + n;
  float ss = 0.f;
  #pragma unroll 16
  for (int c = ch * 64; c < ch * 64 + 64; ++c) {
    float v = xp[(size_t)c * N_];
    ss += v * v;
  }
  ssp[ch][n & 63] = ss;
  __syncthreads();
  if (threadIdx.x < 64) {
    float tot = (ssp[0][threadIdx.x] + ssp[1][threadIdx.x]) +
                (ssp[2][threadIdx.x] + ssp[3][threadIdx.x]);
    invs[threadIdx.x] = 16.0f / fmaxf(sqrtf(tot), 1e-12f);
  }
  __syncthreads();
  float inv = invs[n & 63];
  u16* op = xbT + ((size_t)g * N_ + n) * C_;
  #pragma unroll 2
  for (int c0 = ch * 64; c0 < ch * 64 + 64; c0 += 8) {
    union { bf16x8 v; u16 u[8]; } pk;
    #pragma unroll
    for (int j = 0; j < 8; ++j) pk.u[j] = f2b(xp[(size_t)(c0 + j) * N_] * inv * g1[c0 + j]);
    *(bf16x8*)(op + c0) = pk.v;
  }
}

// ---------------- fused KV-GEMM + exp + PV-accumulate, BK=64 ----------------
__global__ __launch_bounds__(256) void k_kvctx(const u16* __restrict__ Wb,
                                               const u16* __restrict__ XT,
                                               float* __restrict__ ctxp) {
  __shared__ __align__(16) u16 smem[16384];    // 32 KB
  u16* Ws = smem;
  u16* Xs = smem + 8192;
  u16* Pl = smem;
  u16* Vl = smem + 8192;

  int cpx = gridDim.x >> 3;                    // nwg = 64*G, %8==0
  int bid = blockIdx.x;
  int L = (bid & 7) * cpx + (bid >> 3);
  int h = L & 7, nc = (L >> 3) & 7, g = L >> 6;
  int t = threadIdx.x, wave = t >> 6, lane = t & 63;
  int wm = wave >> 1, wn = wave & 1;
  int kg = lane >> 4, lr = lane & 15;

  const u16* WK = Wb + (size_t)(HID + h * DH) * C_;
  const u16* WV = Wb + (size_t)(2 * HID + h * DH) * C_;
  const u16* Xg = XT + ((size_t)g * N_ + nc * 512) * C_;

  int rl8 = lane >> 3;
  int cs8 = (lane & 7) ^ rl8;
  const u16* Wsrc = (wave < 2) ? WK : WV;

  f32x4 acc2[4];
  #pragma unroll
  for (int nf = 0; nf < 4; ++nf) acc2[nf] = (f32x4)0.f;
  float rs[4] = {0.f, 0.f, 0.f, 0.f};

  for (int it = 0; it < 4; ++it) {
    f32x4 acc[4][4];
    #pragma unroll
    for (int i = 0; i < 4; ++i)
      #pragma unroll
      for (int j = 0; j < 4; ++j) acc[i][j] = (f32x4)0.f;

    for (int k0 = 0; k0 < C_; k0 += 64) {
      #pragma unroll
      for (int q = 0; q < 4; ++q) {
        int rb = wave * 32 + q * 8;
        int rw = (rb & 63) + rl8;
        int rx = it * 128 + rb + rl8;
        gld_lds16(Wsrc + (size_t)rw * C_ + k0 + cs8 * 8, Ws + rb * 64);
        gld_lds16(Xg + (size_t)rx * C_ + k0 + cs8 * 8, Xs + rb * 64);
      }
      __syncthreads();
      #pragma unroll
      for (int ks = 0; ks < 2; ++ks) {
        int ch = ks * 4 + kg;
        bf16x8 a[4], bv[4];
        #pragma unroll
        for (int mf = 0; mf < 4; ++mf) {
          int r = wm * 64 + mf * 16 + lr;
          a[mf] = *(const bf16x8*)(Xs + r * 64 + ((ch ^ (r & 7)) * 8));
        }
        #pragma unroll
        for (int nf = 0; nf < 4; ++nf) {
          int r = wn * 64 + nf * 16 + lr;
          bv[nf] = *(const bf16x8*)(Ws + r * 64 + ((ch ^ (r & 7)) * 8));
        }
        #pragma unroll
        for (int mf = 0; mf < 4; ++mf)
          #pragma unroll
          for (int nf = 0; nf < 4; ++nf)
            acc[mf][nf] = __builtin_amdgcn_mfma_f32_16x16x32_bf16(a[mf], bv[nf], acc[mf][nf], 0, 0, 0);
      }
      __syncthreads();
    }

    if (wn == 0) {
      #pragma unroll
      for (int mf = 0; mf < 4; ++mf) {
        int nb = wm * 64 + mf * 16 + kg * 4;
        int cc = nb >> 3, off = nb & 7;
        #pragma unroll
        for (int nf = 0; nf < 4; ++nf) {
          int d = nf * 16 + lr;
          float e0 = __expf(acc[mf][nf][0]);
          float e1 = __expf(acc[mf][nf][1]);
          float e2 = __expf(acc[mf][nf][2]);
          float e3 = __expf(acc[mf][nf][3]);
          rs[nf] += (e0 + e1) + (e2 + e3);
          union { bf16x4 v; u16 u[4]; } pk;
          pk.u[0] = f2b(e0); pk.u[1] = f2b(e1); pk.u[2] = f2b(e2); pk.u[3] = f2b(e3);
          *(bf16x4*)(Pl + d * 128 + ((cc ^ (d & 15)) * 8) + off) = pk.v;
        }
      }
    } else {
      #pragma unroll
      for (int mf = 0; mf < 4; ++mf) {
        int nb = wm * 64 + mf * 16 + kg * 4;
        int cc = nb >> 3, off = nb & 7;
        #pragma unroll
        for (int nf = 0; nf < 4; ++nf) {
          int e = nf * 16 + lr;
          union { bf16x4 v; u16 u[4]; } pk;
          pk.u[0] = f2b(acc[mf][nf][0]); pk.u[1] = f2b(acc[mf][nf][1]);
          pk.u[2] = f2b(acc[mf][nf][2]); pk.u[3] = f2b(acc[mf][nf][3]);
          *(bf16x4*)(Vl + e * 128 + ((cc ^ (e & 15)) * 8) + off) = pk.v;
        }
      }
    }
    __syncthreads();

    #pragma unroll
    for (int k = 0; k < 4; ++k) {
      int c = k * 4 + kg;
      bf16x8 af = *(const bf16x8*)(Pl + (wave * 16 + lr) * 128 + ((c ^ lr) * 8));
      #pragma unroll
      for (int nf = 0; nf < 4; ++nf) {
        bf16x8 bfv = *(const bf16x8*)(Vl + (nf * 16 + lr) * 128 + ((c ^ lr) * 8));
        acc2[nf] = __builtin_amdgcn_mfma_f32_16x16x32_bf16(af, bfv, acc2[nf], 0, 0, 0);
      }
    }
    __syncthreads();
  }

  float* cgp = ctxp + ((size_t)(g * NH + h) * 8 + nc) * CTXS;
  #pragma unroll
  for (int nf = 0; nf < 4; ++nf)
    #pragma unroll
    for (int j = 0; j < 4; ++j) {
      int d = wave * 16 + kg * 4 + j;
      int e = nf * 16 + lr;
      cgp[d * 64 + e] = acc2[nf][j];
    }
  if (wn == 0) {
    #pragma unroll
    for (int nf = 0; nf < 4; ++nf) {
      rs[nf] += __shfl_xor(rs[nf], 16);
      rs[nf] += __shfl_xor(rs[nf], 32);
    }
    if (lane < 16) {
      #pragma unroll
      for (int nf = 0; nf < 4; ++nf)
        cgp[4096 + wm * 64 + nf * 16 + lane] = rs[nf];
    }
  }
}

// ---------------- ctx finalize + Wo2 = Wo_h @ ctx_h^T : wo2[g][c][h*64+d] bf16 ----------------
__global__ __launch_bounds__(256) void k_cwo(const float* __restrict__ ctxp,
                                             const float* __restrict__ memkv,
                                             const u16* __restrict__ Wo,
                                             u16* __restrict__ wo2) {
  int g = blockIdx.y, h = blockIdx.x;
  int t = threadIdx.x, wave = t >> 6, lane = t & 63;
  int kg = lane >> 4, lr = lane & 15;
  int rl8 = lane >> 3, cs8 = (lane & 7) ^ rl8;
  __shared__ float emk[DH * NMEM];
  __shared__ float sd[DH];
  __shared__ __align__(16) u16 Cl[64 * 64];    // ctx[d][e] bf16, swizzled (8 KB)
  __shared__ __align__(16) u16 As2[256 * 64];  // Wo slice rows c x 64 e (32 KB)

  const float* mk = memkv + (size_t)h * DH * NMEM;
  const float* mv = memkv + (size_t)(NH + h) * DH * NMEM;
  const float* cp = ctxp + (size_t)(g * NH + h) * 8 * CTXS;
  emk[t] = __expf(mk[t]);
  __syncthreads();
  if (t < DH) {
    float s = 0.f;
    #pragma unroll
    for (int p = 0; p < 8; ++p)
      s += cp[p * CTXS + 4096 + t] + cp[p * CTXS + 4160 + t];
    #pragma unroll
    for (int j = 0; j < NMEM; ++j) s += emk[t * 4 + j];
    sd[t] = s;
  }
  #pragma unroll
  for (int q = 0; q < 8; ++q) {
    int rb = wave * 64 + q * 8;
    gld_lds16(Wo + (size_t)(rb + rl8) * HID + h * DH + cs8 * 8, As2 + rb * 64);
  }
  __syncthreads();
  #pragma unroll
  for (int i = 0; i < 16; ++i) {
    int idx = t + 256 * i;
    int d = idx >> 6, e = idx & 63;
    float v = 0.f;
    #pragma unroll
    for (int p = 0; p < 8; ++p) v += cp[p * CTXS + idx];
    #pragma unroll
    for (int j = 0; j < NMEM; ++j) v += emk[d * 4 + j] * mv[e * 4 + j];
    Cl[d * 64 + (((e >> 3) ^ (d & 7)) * 8) + (e & 7)] = f2b(v / sd[d]);
  }
  __syncthreads();
  f32x4 acc[4][4];
  #pragma unroll
  for (int i = 0; i < 4; ++i)
    #pragma unroll
    for (int j = 0; j < 4; ++j) acc[i][j] = (f32x4)0.f;
  #pragma unroll
  for (int ks = 0; ks < 2; ++ks) {
    int ch = ks * 4 + kg;
    bf16x8 a[4], b[4];
    #pragma unroll
    for (int mf = 0; mf < 4; ++mf) {
      int r = wave * 64 + mf * 16 + lr;
      a[mf] = *(const bf16x8*)(As2 + r * 64 + ((ch ^ (r & 7)) * 8));
    }
    #pragma unroll
    for (int nf = 0; nf < 4; ++nf) {
      int rd = nf * 16 + lr;
      b[nf] = *(const bf16x8*)(Cl + rd * 64 + ((ch ^ (rd & 7)) * 8));
    }
    #pragma unroll
    for (int mf = 0; mf < 4; ++mf)
      #pragma unroll
      for (int nf = 0; nf < 4; ++nf)
        acc[mf][nf] = __builtin_amdgcn_mfma_f32_16x16x32_bf16(a[mf], b[nf], acc[mf][nf], 0, 0, 0);
  }
  u16* og = wo2 + (size_t)g * 256 * 512;
  #pragma unroll
  for (int mf = 0; mf < 4; ++mf)
    #pragma unroll
    for (int nf = 0; nf < 4; ++nf)
      #pragma unroll
      for (int j = 0; j < 4; ++j) {
        int c = wave * 64 + mf * 16 + kg * 4 + j;
        int dd = nf * 16 + lr;
        og[(size_t)c * 512 + h * DH + dd] = f2b(acc[mf][nf][j]);
      }
}

// ---------------- fused Q-GEMM + q-softmax + out-proj + rmsnorm2, BN=128 ----------------
// 512 threads, 128-n tile. Phase A: Q (512o x 128n, K=256), wave = head.
// Phase B: wave-local softmax; pack qsm to bf16 pairs in REGISTERS (64 VGPR).
// Phase C: out (256c x 128n, K=512 over Wo2) in two 256-o halves via LDS Ql.
__global__ __launch_bounds__(512) void k_qout(const u16* __restrict__ Wq,
                                              const u16* __restrict__ XT,
                                              const u16* __restrict__ Wo2,
                                              const float* __restrict__ bias,
                                              const float* __restrict__ g2,
                                              float* __restrict__ out) {
  __shared__ __align__(16) u16 smem[49152];    // 96 KB
  u16* R0 = smem;            // 32 KB: Wq-stage (512x32) / Wo2-stage (256x64) / part
  u16* R1 = smem + 16384;    // 64 KB: X-tile [128 n][256 c] / Ql half [128 n][256 o]

  int cpx = gridDim.x >> 3;                    // nwg = 32*G, %8==0
  int bid = blockIdx.x;
  int L = (bid & 7) * cpx + (bid >> 3);
  int nc = L & 31, g = L >> 5;
  int t = threadIdx.x, wave = t >> 6, lane = t & 63;
  int kg = lane >> 4, lr = lane & 15;
  int rl4 = lane >> 2, cs4 = (lane & 3) ^ (rl4 & 3);   // 4-chunk rows (64B)
  int rl8 = lane >> 3, cs8 = (lane & 7) ^ rl8;         // 8-chunk rows (128B)

  const u16* Xg = XT + ((size_t)g * N_ + nc * 128) * C_;
  const u16* W2g = Wo2 + (size_t)g * 256 * 512;

  // stage X tile once: [128 n][256 c], low-3-chunk swizzle by n&7
  {
    int xrow_off = lane >> 5;                  // 0..1
    int c32 = lane & 31;
    #pragma unroll
    for (int q = 0; q < 8; ++q) {
      int base = wave * 16 + q * 2;
      int row = base + xrow_off;
      int sw = (c32 & 24) | ((c32 & 7) ^ (row & 7));
      gld_lds16(Xg + (size_t)row * C_ + sw * 8, R1 + base * 256);
    }
  }

  // ---- phase A: Q-GEMM, BK=32, 8 steps, acc 64o x 128n per wave ----
  f32x4 acc[4][8];
  #pragma unroll
  for (int i = 0; i < 4; ++i)
    #pragma unroll
    for (int j = 0; j < 8; ++j) acc[i][j] = (f32x4)0.f;

  for (int k0i = 0; k0i < 8; ++k0i) {
    int k0 = k0i * 32;
    #pragma unroll
    for (int q = 0; q < 4; ++q) {              // Wq slice 512 rows x 32
      int rb = ((wave * 4 + q) & 31) * 16;
      gld_lds16(Wq + (size_t)(rb + rl4) * C_ + k0 + cs4 * 8, R0 + rb * 32);
    }
    __syncthreads();
    bf16x8 a[4], bv[8];
    #pragma unroll
    for (int mf = 0; mf < 4; ++mf) {           // A = Wq rows (o)
      int r = wave * 64 + mf * 16 + lr;
      a[mf] = *(const bf16x8*)(R0 + r * 32 + ((kg ^ (r & 3)) * 8));
    }
    #pragma unroll
    for (int nf = 0; nf < 8; ++nf) {           // B = X rows (n)
      int bn = nf * 16 + lr;
      int c32 = k0i * 4 + kg;
      int sw = (c32 & 24) | ((c32 & 7) ^ (bn & 7));
      bv[nf] = *(const bf16x8*)(R1 + bn * 256 + sw * 8);
    }
    #pragma unroll
    for (int mf = 0; mf < 4; ++mf)
      #pragma unroll
      for (int nf = 0; nf < 8; ++nf)
        acc[mf][nf] = __builtin_amdgcn_mfma_f32_16x16x32_bf16(a[mf], bv[nf], acc[mf][nf], 0, 0, 0);
    __syncthreads();
  }

  // ---- phase B: wave-local softmax; pack to bf16 pairs in registers ----
  float colsum[8];
  #pragma unroll
  for (int nf = 0; nf < 8; ++nf) {
    float s = 0.f;
    #pragma unroll
    for (int mf = 0; mf < 4; ++mf)
      #pragma unroll
      for (int j = 0; j < 4; ++j) {
        float e = __expf(acc[mf][nf][j]);
        acc[mf][nf][j] = e;
        s += e;
      }
    colsum[nf] = s;
  }
  #pragma unroll
  for (int nf = 0; nf < 8; ++nf) {
    colsum[nf] += __shfl_xor(colsum[nf], 16);
    colsum[nf] += __shfl_xor(colsum[nf], 32);
    colsum[nf] = 0.125f / colsum[nf];
  }
  unsigned pq[4][8][2];                        // packed qsm, 64 VGPRs (acc dies here)
  #pragma unroll
  for (int nf = 0; nf < 8; ++nf) {
    float invs = colsum[nf];
    #pragma unroll
    for (int mf = 0; mf < 4; ++mf)
      #pragma unroll
      for (int jp = 0; jp < 2; ++jp) {
        u16 lo = f2b(acc[mf][nf][jp * 2] * invs);
        u16 hi = f2b(acc[mf][nf][jp * 2 + 1] * invs);
        pq[mf][nf][jp] = (unsigned)lo | ((unsigned)hi << 16);
      }
  }

  f32x4 acc2[2][8];
  #pragma unroll
  for (int i = 0; i < 2; ++i)
    #pragma unroll
    for (int j = 0; j < 8; ++j) acc2[i][j] = (f32x4)0.f;

  #pragma unroll
  for (int half = 0; half < 2; ++half) {
    if ((wave >> 2) == half) {
      #pragma unroll
      for (int nf = 0; nf < 8; ++nf) {
        int n = nf * 16 + lr;
        #pragma unroll
        for (int mf = 0; mf < 4; ++mf)
          #pragma unroll
          for (int jp = 0; jp < 2; ++jp) {
            int oc = (wave & 3) * 64 + mf * 16 + kg * 4 + jp * 2;
            int c8 = oc >> 3;
            int sw = (c8 & 24) | ((c8 & 7) ^ (n & 7));
            *(unsigned*)(R1 + n * 256 + sw * 8 + (oc & 7)) = pq[mf][nf][jp];
          }
      }
    }
    __syncthreads();
    // ---- phase C (this K-half): out-GEMM, 4 k0-steps of 64 ----
    for (int k0l = 0; k0l < 4; ++k0l) {
      int cb = half * 256 + k0l * 64;
      #pragma unroll
      for (int q = 0; q < 4; ++q) {            // Wo2 slice 256 rows x 64
        int rb = ((wave * 4 + q) & 31) * 8;
        gld_lds16(W2g + (size_t)(rb + rl8) * 512 + cb + cs8 * 8, R0 + rb * 64);
      }
      __syncthreads();
      #pragma unroll
      for (int ks = 0; ks < 2; ++ks) {
        int ch = ks * 4 + kg;
        bf16x8 a2[2], b2[8];
        #pragma unroll
        for (int mf = 0; mf < 2; ++mf) {       // A = Wo2 rows (c), 32 per wave
          int r = wave * 32 + mf * 16 + lr;
          a2[mf] = *(const bf16x8*)(R0 + r * 64 + ((ch ^ (r & 7)) * 8));
        }
        #pragma unroll
        for (int nf = 0; nf < 8; ++nf) {       // B = Ql rows (n)
          int bn = nf * 16 + lr;
          int c8 = k0l * 8 + ks * 4 + kg;
          int sw = (c8 & 24) | ((c8 & 7) ^ (bn & 7));
          b2[nf] = *(const bf16x8*)(R1 + bn * 256 + sw * 8);
        }
        #pragma unroll
        for (int mf = 0; mf < 2; ++mf)
          #pragma unroll
          for (int nf = 0; nf < 8; ++nf)
            acc2[mf][nf] = __builtin_amdgcn_mfma_f32_16x16x32_bf16(a2[mf], b2[nf], acc2[mf][nf], 0, 0, 0);
      }
      __syncthreads();
    }
  }

  // ---- epilogue: bias + rmsnorm over c (256 rows) + store ----
  float colsq[8] = {0.f, 0.f, 0.f, 0.f, 0.f, 0.f, 0.f, 0.f};
  #pragma unroll
  for (int mf = 0; mf < 2; ++mf)
    #pragma unroll
    for (int j = 0; j < 4; ++j) {
      int c = wave * 32 + mf * 16 + kg * 4 + j;
      float bs = bias[c];
      #pragma unroll
      for (int nf = 0; nf < 8; ++nf) {
        float v = acc2[mf][nf][j] + bs;
        acc2[mf][nf][j] = v;
        colsq[nf] += v * v;
      }
    }
  #pragma unroll
  for (int nf = 0; nf < 8; ++nf) {
    colsq[nf] += __shfl_xor(colsq[nf], 16);
    colsq[nf] += __shfl_xor(colsq[nf], 32);
  }
  float* part = (float*)R0;                    // 8 x 128 f32 = 4 KB
  if (kg == 0) {
    #pragma unroll
    for (int nf = 0; nf < 8; ++nf) part[wave * 128 + nf * 16 + lr] = colsq[nf];
  }
  __syncthreads();
  float* og = out + (size_t)g * C_ * N_ + nc * 128;
  #pragma unroll
  for (int nf = 0; nf < 8; ++nf) {
    int col = nf * 16 + lr;
    float tot = 0.f;
    #pragma unroll
    for (int w = 0; w < 8; ++w) tot += part[w * 128 + col];
    float invn = 16.0f / fmaxf(sqrtf(tot), 1e-12f);
    #pragma unroll
    for (int mf = 0; mf < 2; ++mf)
      #pragma unroll
      for (int j = 0; j < 4; ++j) {
        int c = wave * 32 + mf * 16 + kg * 4 + j;
        og[(size_t)c * N_ + col] = acc2[mf][nf][j] * invn * g2[c];
      }
  }
}

extern "C" void kernel_launch(void* const* d_in, const int* in_sizes, int n_in,
                              void* d_out, int out_size, void* d_ws, size_t ws_size,
                              hipStream_t stream) {
  (void)in_sizes; (void)n_in; (void)out_size;
  const float* x      = (const float*)d_in[0];
  const float* gain1  = (const float*)d_in[1];
  const float* w_qkv  = (const float*)d_in[2];
  const float* mem_kv = (const float*)d_in[3];
  const float* w_out  = (const float*)d_in[4];
  const float* b_out  = (const float*)d_in[5];
  const float* gain2  = (const float*)d_in[6];
  float* out = (float*)d_out;

  char* ws = (char*)d_ws;
  u16* wqkvb = (u16*)ws;                         // 786,432 B
  u16* woutb = (u16*)(ws + 786432);              // 262,144 B
  size_t shared_b = 1048576;

  const size_t xbT_b  = (size_t)N_ * C_ * 2;           //  2 MiB
  const size_t ctxp_b = (size_t)NH * 8 * CTXS * 4;     // ~1.03 MiB
  const size_t wo2_b  = (size_t)256 * 512 * 2;         // 256 KiB
  const size_t per_b  = xbT_b + ctxp_b + wo2_b;

  int G = 16;
  while (G > 1 && shared_b + (size_t)G * per_b > ws_size) G >>= 1;

  char* base = ws + shared_b;
  u16*   xbT  = (u16*)base;
  float* ctxp = (float*)(base + (size_t)G * xbT_b);
  u16*   wo2  = (u16*)(base + (size_t)G * (xbT_b + ctxp_b));

  k_cvtw<<<256, 256, 0, stream>>>(w_qkv, w_out, wqkvb, woutb);

  for (int b0 = 0; b0 < B_; b0 += G) {
    const float* xc = x + (size_t)b0 * C_ * N_;
    float*       oc = out + (size_t)b0 * C_ * N_;
    k_rms1  <<<dim3(N_ / 64, G),   256, 0, stream>>>(xc, gain1, xbT);
    k_kvctx <<<dim3(64 * G),       256, 0, stream>>>(wqkvb, xbT, ctxp);
    k_cwo   <<<dim3(NH, G),        256, 0, stream>>>(ctxp, mem_kv, woutb, wo2);
    k_qout  <<<dim3(32 * G),       512, 0, stream>>>(wqkvb, xbT, wo2, b_out, gain2, oc);
  }
}

// Round 16
// 161.430 us; speedup vs baseline: 1.0713x; 1.0203x over previous
//
#include <hip/hip_runtime.h>

typedef __attribute__((ext_vector_type(8))) short bf16x8;
typedef __attribute__((ext_vector_type(4))) short bf16x4;
typedef __attribute__((ext_vector_type(4))) float f32x4;
typedef unsigned short u16;

constexpr int B_   = 16;
constexpr int C_   = 256;
constexpr int NH   = 8;
constexpr int DH   = 64;
constexpr int NMEM = 4;
constexpr int HID  = 512;    // NH*DH
constexpr int QKVC = 1536;   // 3*HID
constexpr int N_   = 4096;   // 64*64
constexpr int CTXS = 4224;   // per-nc ctxp stride: 4096 ctx + 128 rsum slots

// lgkm-only barrier: keeps global (vmcnt) prefetch loads in flight
#define SBAR() asm volatile("s_waitcnt lgkmcnt(0)\ns_barrier" ::: "memory")
// full drain barrier (prologue only)
#define KBAR() asm volatile("s_waitcnt vmcnt(0) lgkmcnt(0)\ns_barrier" ::: "memory")

__device__ __forceinline__ u16 f2b(float f) {   // RNE f32->bf16
  union { float f; unsigned u; } v{f};
  unsigned r = v.u + 0x7fff + ((v.u >> 16) & 1);
  return (u16)(r >> 16);
}
__device__ __forceinline__ float b2f(u16 h) {
  union { unsigned u; float f; } v; v.u = ((unsigned)h) << 16; return v.f;
}

// async global->LDS, 16B per lane; lds dest = wave-uniform base + lane*16B
__device__ __forceinline__ void gld_lds16(const u16* g, u16* l) {
  __builtin_amdgcn_global_load_lds(
      (const __attribute__((address_space(1))) unsigned*)g,
      (__attribute__((address_space(3))) unsigned*)l, 16, 0, 0);
}

// ---------------- weights -> bf16 (once per call) ----------------
__global__ void k_cvtw(const float* __restrict__ wq, const float* __restrict__ wo,
                       u16* __restrict__ wqb, u16* __restrict__ wob) {
  int i = blockIdx.x * 256 + threadIdx.x;
  for (int idx = i; idx < QKVC * C_; idx += gridDim.x * 256) wqb[idx] = f2b(wq[idx]);
  for (int idx = i; idx < C_ * HID; idx += gridDim.x * 256) wob[idx] = f2b(wo[idx]);
}

// ---------------- rmsnorm1 + transpose to bf16 [g][n][c] ----------------
__global__ __launch_bounds__(256) void k_rms1(const float* __restrict__ x,
                                              const float* __restrict__ g1,
                                              u16* __restrict__ xbT) {
  int g = blockIdx.y;
  int n = blockIdx.x * 64 + (threadIdx.x & 63);
  int ch = threadIdx.x >> 6;                   // c-quarter 0..3
  __shared__ float ssp[4][64];
  __shared__ float invs[64];
  const float* xp = x + (size_t)g * C_ * N_ + n;
  float ss = 0.f;
  #pragma unroll 16
  for (int c = ch * 64; c < ch * 64 + 64; ++c) {
    float v = xp[(size_t)c * N_];
    ss += v * v;
  }
  ssp[ch][n & 63] = ss;
  __syncthreads();
  if (threadIdx.x < 64) {
    float tot = (ssp[0][threadIdx.x] + ssp[1][threadIdx.x]) +
                (ssp[2][threadIdx.x] + ssp[3][threadIdx.x]);
    invs[threadIdx.x] = 16.0f / fmaxf(sqrtf(tot), 1e-12f);
  }
  __syncthreads();
  float inv = invs[n & 63];
  u16* op = xbT + ((size_t)g * N_ + n) * C_;
  #pragma unroll 2
  for (int c0 = ch * 64; c0 < ch * 64 + 64; c0 += 8) {
    union { bf16x8 v; u16 u[8]; } pk;
    #pragma unroll
    for (int j = 0; j < 8; ++j) pk.u[j] = f2b(xp[(size_t)(c0 + j) * N_] * inv * g1[c0 + j]);
    *(bf16x8*)(op + c0) = pk.v;
  }
}

// ---------------- fused KV-GEMM + exp + PV-accumulate, BK=64 ----------------
__global__ __launch_bounds__(256) void k_kvctx(const u16* __restrict__ Wb,
                                               const u16* __restrict__ XT,
                                               float* __restrict__ ctxp) {
  __shared__ __align__(16) u16 smem[16384];    // 32 KB
  u16* Ws = smem;
  u16* Xs = smem + 8192;
  u16* Pl = smem;
  u16* Vl = smem + 8192;

  int cpx = gridDim.x >> 3;                    // nwg = 64*G, %8==0
  int bid = blockIdx.x;
  int L = (bid & 7) * cpx + (bid >> 3);
  int h = L & 7, nc = (L >> 3) & 7, g = L >> 6;
  int t = threadIdx.x, wave = t >> 6, lane = t & 63;
  int wm = wave >> 1, wn = wave & 1;
  int kg = lane >> 4, lr = lane & 15;

  const u16* WK = Wb + (size_t)(HID + h * DH) * C_;
  const u16* WV = Wb + (size_t)(2 * HID + h * DH) * C_;
  const u16* Xg = XT + ((size_t)g * N_ + nc * 512) * C_;

  int rl8 = lane >> 3;
  int cs8 = (lane & 7) ^ rl8;
  const u16* Wsrc = (wave < 2) ? WK : WV;

  f32x4 acc2[4];
  #pragma unroll
  for (int nf = 0; nf < 4; ++nf) acc2[nf] = (f32x4)0.f;
  float rs[4] = {0.f, 0.f, 0.f, 0.f};

  for (int it = 0; it < 4; ++it) {
    f32x4 acc[4][4];
    #pragma unroll
    for (int i = 0; i < 4; ++i)
      #pragma unroll
      for (int j = 0; j < 4; ++j) acc[i][j] = (f32x4)0.f;

    for (int k0 = 0; k0 < C_; k0 += 64) {
      #pragma unroll
      for (int q = 0; q < 4; ++q) {
        int rb = wave * 32 + q * 8;
        int rw = (rb & 63) + rl8;
        int rx = it * 128 + rb + rl8;
        gld_lds16(Wsrc + (size_t)rw * C_ + k0 + cs8 * 8, Ws + rb * 64);
        gld_lds16(Xg + (size_t)rx * C_ + k0 + cs8 * 8, Xs + rb * 64);
      }
      __syncthreads();
      #pragma unroll
      for (int ks = 0; ks < 2; ++ks) {
        int ch = ks * 4 + kg;
        bf16x8 a[4], bv[4];
        #pragma unroll
        for (int mf = 0; mf < 4; ++mf) {
          int r = wm * 64 + mf * 16 + lr;
          a[mf] = *(const bf16x8*)(Xs + r * 64 + ((ch ^ (r & 7)) * 8));
        }
        #pragma unroll
        for (int nf = 0; nf < 4; ++nf) {
          int r = wn * 64 + nf * 16 + lr;
          bv[nf] = *(const bf16x8*)(Ws + r * 64 + ((ch ^ (r & 7)) * 8));
        }
        #pragma unroll
        for (int mf = 0; mf < 4; ++mf)
          #pragma unroll
          for (int nf = 0; nf < 4; ++nf)
            acc[mf][nf] = __builtin_amdgcn_mfma_f32_16x16x32_bf16(a[mf], bv[nf], acc[mf][nf], 0, 0, 0);
      }
      __syncthreads();
    }

    if (wn == 0) {
      #pragma unroll
      for (int mf = 0; mf < 4; ++mf) {
        int nb = wm * 64 + mf * 16 + kg * 4;
        int cc = nb >> 3, off = nb & 7;
        #pragma unroll
        for (int nf = 0; nf < 4; ++nf) {
          int d = nf * 16 + lr;
          float e0 = __expf(acc[mf][nf][0]);
          float e1 = __expf(acc[mf][nf][1]);
          float e2 = __expf(acc[mf][nf][2]);
          float e3 = __expf(acc[mf][nf][3]);
          rs[nf] += (e0 + e1) + (e2 + e3);
          union { bf16x4 v; u16 u[4]; } pk;
          pk.u[0] = f2b(e0); pk.u[1] = f2b(e1); pk.u[2] = f2b(e2); pk.u[3] = f2b(e3);
          *(bf16x4*)(Pl + d * 128 + ((cc ^ (d & 15)) * 8) + off) = pk.v;
        }
      }
    } else {
      #pragma unroll
      for (int mf = 0; mf < 4; ++mf) {
        int nb = wm * 64 + mf * 16 + kg * 4;
        int cc = nb >> 3, off = nb & 7;
        #pragma unroll
        for (int nf = 0; nf < 4; ++nf) {
          int e = nf * 16 + lr;
          union { bf16x4 v; u16 u[4]; } pk;
          pk.u[0] = f2b(acc[mf][nf][0]); pk.u[1] = f2b(acc[mf][nf][1]);
          pk.u[2] = f2b(acc[mf][nf][2]); pk.u[3] = f2b(acc[mf][nf][3]);
          *(bf16x4*)(Vl + e * 128 + ((cc ^ (e & 15)) * 8) + off) = pk.v;
        }
      }
    }
    __syncthreads();

    #pragma unroll
    for (int k = 0; k < 4; ++k) {
      int c = k * 4 + kg;
      bf16x8 af = *(const bf16x8*)(Pl + (wave * 16 + lr) * 128 + ((c ^ lr) * 8));
      #pragma unroll
      for (int nf = 0; nf < 4; ++nf) {
        bf16x8 bfv = *(const bf16x8*)(Vl + (nf * 16 + lr) * 128 + ((c ^ lr) * 8));
        acc2[nf] = __builtin_amdgcn_mfma_f32_16x16x32_bf16(af, bfv, acc2[nf], 0, 0, 0);
      }
    }
    __syncthreads();
  }

  float* cgp = ctxp + ((size_t)(g * NH + h) * 8 + nc) * CTXS;
  #pragma unroll
  for (int nf = 0; nf < 4; ++nf)
    #pragma unroll
    for (int j = 0; j < 4; ++j) {
      int d = wave * 16 + kg * 4 + j;
      int e = nf * 16 + lr;
      cgp[d * 64 + e] = acc2[nf][j];
    }
  if (wn == 0) {
    #pragma unroll
    for (int nf = 0; nf < 4; ++nf) {
      rs[nf] += __shfl_xor(rs[nf], 16);
      rs[nf] += __shfl_xor(rs[nf], 32);
    }
    if (lane < 16) {
      #pragma unroll
      for (int nf = 0; nf < 4; ++nf)
        cgp[4096 + wm * 64 + nf * 16 + lane] = rs[nf];
    }
  }
}

// ---------------- ctx finalize + Wo2 = Wo_h @ ctx_h^T : wo2[g][c][h*64+d] bf16 ----------------
__global__ __launch_bounds__(256) void k_cwo(const float* __restrict__ ctxp,
                                             const float* __restrict__ memkv,
                                             const u16* __restrict__ Wo,
                                             u16* __restrict__ wo2) {
  int g = blockIdx.y, h = blockIdx.x;
  int t = threadIdx.x, wave = t >> 6, lane = t & 63;
  int kg = lane >> 4, lr = lane & 15;
  int rl8 = lane >> 3, cs8 = (lane & 7) ^ rl8;
  __shared__ float emk[DH * NMEM];
  __shared__ float sd[DH];
  __shared__ __align__(16) u16 Cl[64 * 64];    // ctx[d][e] bf16, swizzled (8 KB)
  __shared__ __align__(16) u16 As2[256 * 64];  // Wo slice rows c x 64 e (32 KB)

  const float* mk = memkv + (size_t)h * DH * NMEM;
  const float* mv = memkv + (size_t)(NH + h) * DH * NMEM;
  const float* cp = ctxp + (size_t)(g * NH + h) * 8 * CTXS;
  emk[t] = __expf(mk[t]);
  __syncthreads();
  if (t < DH) {
    float s = 0.f;
    #pragma unroll
    for (int p = 0; p < 8; ++p)
      s += cp[p * CTXS + 4096 + t] + cp[p * CTXS + 4160 + t];
    #pragma unroll
    for (int j = 0; j < NMEM; ++j) s += emk[t * 4 + j];
    sd[t] = s;
  }
  #pragma unroll
  for (int q = 0; q < 8; ++q) {
    int rb = wave * 64 + q * 8;
    gld_lds16(Wo + (size_t)(rb + rl8) * HID + h * DH + cs8 * 8, As2 + rb * 64);
  }
  __syncthreads();
  #pragma unroll
  for (int i = 0; i < 16; ++i) {
    int idx = t + 256 * i;
    int d = idx >> 6, e = idx & 63;
    float v = 0.f;
    #pragma unroll
    for (int p = 0; p < 8; ++p) v += cp[p * CTXS + idx];
    #pragma unroll
    for (int j = 0; j < NMEM; ++j) v += emk[d * 4 + j] * mv[e * 4 + j];
    Cl[d * 64 + (((e >> 3) ^ (d & 7)) * 8) + (e & 7)] = f2b(v / sd[d]);
  }
  __syncthreads();
  f32x4 acc[4][4];
  #pragma unroll
  for (int i = 0; i < 4; ++i)
    #pragma unroll
    for (int j = 0; j < 4; ++j) acc[i][j] = (f32x4)0.f;
  #pragma unroll
  for (int ks = 0; ks < 2; ++ks) {
    int ch = ks * 4 + kg;
    bf16x8 a[4], b[4];
    #pragma unroll
    for (int mf = 0; mf < 4; ++mf) {
      int r = wave * 64 + mf * 16 + lr;
      a[mf] = *(const bf16x8*)(As2 + r * 64 + ((ch ^ (r & 7)) * 8));
    }
    #pragma unroll
    for (int nf = 0; nf < 4; ++nf) {
      int rd = nf * 16 + lr;
      b[nf] = *(const bf16x8*)(Cl + rd * 64 + ((ch ^ (rd & 7)) * 8));
    }
    #pragma unroll
    for (int mf = 0; mf < 4; ++mf)
      #pragma unroll
      for (int nf = 0; nf < 4; ++nf)
        acc[mf][nf] = __builtin_amdgcn_mfma_f32_16x16x32_bf16(a[mf], b[nf], acc[mf][nf], 0, 0, 0);
  }
  u16* og = wo2 + (size_t)g * 256 * 512;
  #pragma unroll
  for (int mf = 0; mf < 4; ++mf)
    #pragma unroll
    for (int nf = 0; nf < 4; ++nf)
      #pragma unroll
      for (int j = 0; j < 4; ++j) {
        int c = wave * 64 + mf * 16 + kg * 4 + j;
        int dd = nf * 16 + lr;
        og[(size_t)c * 512 + h * DH + dd] = f2b(acc[mf][nf][j]);
      }
}

// ---------------- fused Q-GEMM + q-softmax + out-proj + rmsnorm2, BN=128 ----------------
// 512 threads, 1 block/CU. T14 reg-staged prefetch: Wq/Wo2 slices loaded
// global->reg one step ahead (linear, coalesced), ds_write'd to swizzled LDS;
// lgkm-only barriers keep the prefetch in flight across compute.
__global__ __launch_bounds__(512) __attribute__((amdgpu_waves_per_eu(2, 2)))
void k_qout(const u16* __restrict__ Wq,
            const u16* __restrict__ XT,
            const u16* __restrict__ Wo2,
            const float* __restrict__ bias,
            const float* __restrict__ g2,
            float* __restrict__ out) {
  __shared__ __align__(16) u16 smem[49152];    // 96 KB
  u16* R0 = smem;            // 32 KB: Wq-stage (512x32) / Wo2-stage (256x64) / part
  u16* R1 = smem + 16384;    // 64 KB: X-tile [128 n][256 c] / Ql half [128 n][256 o]

  int cpx = gridDim.x >> 3;                    // nwg = 32*G, %8==0
  int bid = blockIdx.x;
  int L = (bid & 7) * cpx + (bid >> 3);
  int nc = L & 31, g = L >> 5;
  int t = threadIdx.x, wave = t >> 6, lane = t & 63;
  int kg = lane >> 4, lr = lane & 15;
  int rl4 = lane >> 2;                         // 16-row groups (phase A)
  int rl8 = lane >> 3;                         // 8-row groups (phase C)
  int ch4 = lane & 3, ch8 = lane & 7;

  const u16* Xg = XT + ((size_t)g * N_ + nc * 128) * C_;
  const u16* W2g = Wo2 + (size_t)g * 256 * 512;

  // stage X tile once (gld_lds): [128 n][256 c], low-3-chunk swizzle by n&7
  {
    int xrow_off = lane >> 5;                  // 0..1
    int c32 = lane & 31;
    #pragma unroll
    for (int q = 0; q < 8; ++q) {
      int base = wave * 16 + q * 2;
      int row = base + xrow_off;
      int sw = (c32 & 24) | ((c32 & 7) ^ (row & 7));
      gld_lds16(Xg + (size_t)row * C_ + sw * 8, R1 + base * 256);
    }
  }

  bf16x8 wreg[4], wo2reg[4];
  // prefetch Wq slice 0 (linear global read)
  #pragma unroll
  for (int q = 0; q < 4; ++q) {
    int r = ((wave * 4 + q) & 31) * 16 + rl4;
    wreg[q] = *(const bf16x8*)(Wq + (size_t)r * C_ + ch4 * 8);
  }
  KBAR();                                      // X landed; wreg ready

  // ---- phase A: Q-GEMM, BK=32, 8 steps, acc 64o x 128n per wave ----
  f32x4 acc[4][8];
  #pragma unroll
  for (int i = 0; i < 4; ++i)
    #pragma unroll
    for (int j = 0; j < 8; ++j) acc[i][j] = (f32x4)0.f;

  #pragma unroll
  for (int k0i = 0; k0i < 8; ++k0i) {
    // ds_write slice k0i (swizzled dest)
    #pragma unroll
    for (int q = 0; q < 4; ++q) {
      int r = ((wave * 4 + q) & 31) * 16 + rl4;
      *(bf16x8*)(R0 + r * 32 + ((ch4 ^ (r & 3)) * 8)) = wreg[q];
    }
    // prefetch next slice (stays in flight across SBARs)
    if (k0i < 7) {
      #pragma unroll
      for (int q = 0; q < 4; ++q) {
        int r = ((wave * 4 + q) & 31) * 16 + rl4;
        wreg[q] = *(const bf16x8*)(Wq + (size_t)r * C_ + (k0i + 1) * 32 + ch4 * 8);
      }
    } else {                                   // prefetch Wo2 slice 0 instead
      #pragma unroll
      for (int q = 0; q < 4; ++q) {
        int r = ((wave * 4 + q) & 31) * 8 + rl8;
        wo2reg[q] = *(const bf16x8*)(W2g + (size_t)r * 512 + ch8 * 8);
      }
    }
    SBAR();                                    // slice visible
    bf16x8 a[4], bv[8];
    #pragma unroll
    for (int mf = 0; mf < 4; ++mf) {           // A = Wq rows (o)
      int r = wave * 64 + mf * 16 + lr;
      a[mf] = *(const bf16x8*)(R0 + r * 32 + ((kg ^ (r & 3)) * 8));
    }
    #pragma unroll
    for (int nf = 0; nf < 8; ++nf) {           // B = X rows (n)
      int bn = nf * 16 + lr;
      int c32 = k0i * 4 + kg;
      int sw = (c32 & 24) | ((c32 & 7) ^ (bn & 7));
      bv[nf] = *(const bf16x8*)(R1 + bn * 256 + sw * 8);
    }
    #pragma unroll
    for (int mf = 0; mf < 4; ++mf)
      #pragma unroll
      for (int nf = 0; nf < 8; ++nf)
        acc[mf][nf] = __builtin_amdgcn_mfma_f32_16x16x32_bf16(a[mf], bv[nf], acc[mf][nf], 0, 0, 0);
    SBAR();                                    // reads done; R0 free
  }

  // ---- phase B: wave-local softmax; pack to bf16 pairs in registers ----
  float colsum[8];
  #pragma unroll
  for (int nf = 0; nf < 8; ++nf) {
    float s = 0.f;
    #pragma unroll
    for (int mf = 0; mf < 4; ++mf)
      #pragma unroll
      for (int j = 0; j < 4; ++j) {
        float e = __expf(acc[mf][nf][j]);
        acc[mf][nf][j] = e;
        s += e;
      }
    colsum[nf] = s;
  }
  #pragma unroll
  for (int nf = 0; nf < 8; ++nf) {
    colsum[nf] += __shfl_xor(colsum[nf], 16);
    colsum[nf] += __shfl_xor(colsum[nf], 32);
    colsum[nf] = 0.125f / colsum[nf];
  }
  unsigned pq[4][8][2];                        // packed qsm (acc dies here)
  #pragma unroll
  for (int nf = 0; nf < 8; ++nf) {
    float invs = colsum[nf];
    #pragma unroll
    for (int mf = 0; mf < 4; ++mf)
      #pragma unroll
      for (int jp = 0; jp < 2; ++jp) {
        u16 lo = f2b(acc[mf][nf][jp * 2] * invs);
        u16 hi = f2b(acc[mf][nf][jp * 2 + 1] * invs);
        pq[mf][nf][jp] = (unsigned)lo | ((unsigned)hi << 16);
      }
  }

  f32x4 acc2[2][8];
  #pragma unroll
  for (int i = 0; i < 2; ++i)
    #pragma unroll
    for (int j = 0; j < 8; ++j) acc2[i][j] = (f32x4)0.f;

  #pragma unroll
  for (int half = 0; half < 2; ++half) {
    // (phase A's / previous half's R1 reads are behind the trailing SBAR)
    if ((wave >> 2) == half) {
      #pragma unroll
      for (int nf = 0; nf < 8; ++nf) {
        int n = nf * 16 + lr;
        #pragma unroll
        for (int mf = 0; mf < 4; ++mf)
          #pragma unroll
          for (int jp = 0; jp < 2; ++jp) {
            int oc = (wave & 3) * 64 + mf * 16 + kg * 4 + jp * 2;
            int c8 = oc >> 3;
            int sw = (c8 & 24) | ((c8 & 7) ^ (n & 7));
            *(unsigned*)(R1 + n * 256 + sw * 8 + (oc & 7)) = pq[mf][nf][jp];
          }
      }
    }
    SBAR();                                    // Ql visible
    // ---- phase C (this K-half): out-GEMM, 4 k0-steps of 64 ----
    #pragma unroll
    for (int k0l = 0; k0l < 4; ++k0l) {
      // ds_write Wo2 slice (swizzled dest)
      #pragma unroll
      for (int q = 0; q < 4; ++q) {
        int r = ((wave * 4 + q) & 31) * 8 + rl8;
        *(bf16x8*)(R0 + r * 64 + ((ch8 ^ (r & 7)) * 8)) = wo2reg[q];
      }
      // prefetch next Wo2 slice
      if (half * 4 + k0l < 7) {
        int cbn = (half * 4 + k0l + 1) * 64;
        #pragma unroll
        for (int q = 0; q < 4; ++q) {
          int r = ((wave * 4 + q) & 31) * 8 + rl8;
          wo2reg[q] = *(const bf16x8*)(W2g + (size_t)r * 512 + cbn + ch8 * 8);
        }
      }
      SBAR();                                  // slice visible
      #pragma unroll
      for (int ks = 0; ks < 2; ++ks) {
        int ch = ks * 4 + kg;
        bf16x8 a2[2], b2[8];
        #pragma unroll
        for (int mf = 0; mf < 2; ++mf) {       // A = Wo2 rows (c), 32 per wave
          int r = wave * 32 + mf * 16 + lr;
          a2[mf] = *(const bf16x8*)(R0 + r * 64 + ((ch ^ (r & 7)) * 8));
        }
        #pragma unroll
        for (int nf = 0; nf < 8; ++nf) {       // B = Ql rows (n)
          int bn = nf * 16 + lr;
          int c8 = k0l * 8 + ks * 4 + kg;
          int sw = (c8 & 24) | ((c8 & 7) ^ (bn & 7));
          b2[nf] = *(const bf16x8*)(R1 + bn * 256 + sw * 8);
        }
        #pragma unroll
        for (int mf = 0; mf < 2; ++mf)
          #pragma unroll
          for (int nf = 0; nf < 8; ++nf)
            acc2[mf][nf] = __builtin_amdgcn_mfma_f32_16x16x32_bf16(a2[mf], b2[nf], acc2[mf][nf], 0, 0, 0);
      }
      SBAR();                                  // reads done; R0/R1 free
    }
  }

  // ---- epilogue: bias + rmsnorm over c (256 rows) + store ----
  float colsq[8] = {0.f, 0.f, 0.f, 0.f, 0.f, 0.f, 0.f, 0.f};
  #pragma unroll
  for (int mf = 0; mf < 2; ++mf)
    #pragma unroll
    for (int j = 0; j < 4; ++j) {
      int c = wave * 32 + mf * 16 + kg * 4 + j;
      float bs = bias[c];
      #pragma unroll
      for (int nf = 0; nf < 8; ++nf) {
        float v = acc2[mf][nf][j] + bs;
        acc2[mf][nf][j] = v;
        colsq[nf] += v * v;
      }
    }
  #pragma unroll
  for (int nf = 0; nf < 8; ++nf) {
    colsq[nf] += __shfl_xor(colsq[nf], 16);
    colsq[nf] += __shfl_xor(colsq[nf], 32);
  }
  float* part = (float*)R0;                    // 8 x 128 f32 = 4 KB
  if (kg == 0) {
    #pragma unroll
    for (int nf = 0; nf < 8; ++nf) part[wave * 128 + nf * 16 + lr] = colsq[nf];
  }
  __syncthreads();
  float* og = out + (size_t)g * C_ * N_ + nc * 128;
  #pragma unroll
  for (int nf = 0; nf < 8; ++nf) {
    int col = nf * 16 + lr;
    float tot = 0.f;
    #pragma unroll
    for (int w = 0; w < 8; ++w) tot += part[w * 128 + col];
    float invn = 16.0f / fmaxf(sqrtf(tot), 1e-12f);
    #pragma unroll
    for (int mf = 0; mf < 2; ++mf)
      #pragma unroll
      for (int j = 0; j < 4; ++j) {
        int c = wave * 32 + mf * 16 + kg * 4 + j;
        og[(size_t)c * N_ + col] = acc2[mf][nf][j] * invn * g2[c];
      }
  }
}

extern "C" void kernel_launch(void* const* d_in, const int* in_sizes, int n_in,
                              void* d_out, int out_size, void* d_ws, size_t ws_size,
                              hipStream_t stream) {
  (void)in_sizes; (void)n_in; (void)out_size;
  const float* x      = (const float*)d_in[0];
  const float* gain1  = (const float*)d_in[1];
  const float* w_qkv  = (const float*)d_in[2];
  const float* mem_kv = (const float*)d_in[3];
  const float* w_out  = (const float*)d_in[4];
  const float* b_out  = (const float*)d_in[5];
  const float* gain2  = (const float*)d_in[6];
  float* out = (float*)d_out;

  char* ws = (char*)d_ws;
  u16* wqkvb = (u16*)ws;                         // 786,432 B
  u16* woutb = (u16*)(ws + 786432);              // 262,144 B
  size_t shared_b = 1048576;

  const size_t xbT_b  = (size_t)N_ * C_ * 2;           //  2 MiB
  const size_t ctxp_b = (size_t)NH * 8 * CTXS * 4;     // ~1.03 MiB
  const size_t wo2_b  = (size_t)256 * 512 * 2;         // 256 KiB
  const size_t per_b  = xbT_b + ctxp_b + wo2_b;

  int G = 16;
  while (G > 1 && shared_b + (size_t)G * per_b > ws_size) G >>= 1;

  char* base = ws + shared_b;
  u16*   xbT  = (u16*)base;
  float* ctxp = (float*)(base + (size_t)G * xbT_b);
  u16*   wo2  = (u16*)(base + (size_t)G * (xbT_b + ctxp_b));

  k_cvtw<<<256, 256, 0, stream>>>(w_qkv, w_out, wqkvb, woutb);

  for (int b0 = 0; b0 < B_; b0 += G) {
    const float* xc = x + (size_t)b0 * C_ * N_;
    float*       oc = out + (size_t)b0 * C_ * N_;
    k_rms1  <<<dim3(N_ / 64, G),   256, 0, stream>>>(xc, gain1, xbT);
    k_kvctx <<<dim3(64 * G),       256, 0, stream>>>(wqkvb, xbT, ctxp);
    k_cwo   <<<dim3(NH, G),        256, 0, stream>>>(ctxp, mem_kv, woutb, wo2);
    k_qout  <<<dim3(32 * G),       512, 0, stream>>>(wqkvb, xbT, wo2, b_out, gain2, oc);
  }
}

// Round 17
// 161.382 us; speedup vs baseline: 1.0716x; 1.0003x over previous
//
#include <hip/hip_runtime.h>

typedef __attribute__((ext_vector_type(8))) short bf16x8;
typedef __attribute__((ext_vector_type(4))) short bf16x4;
typedef __attribute__((ext_vector_type(4))) float f32x4;
typedef unsigned short u16;

constexpr int B_   = 16;
constexpr int C_   = 256;
constexpr int NH   = 8;
constexpr int DH   = 64;
constexpr int NMEM = 4;
constexpr int HID  = 512;    // NH*DH
constexpr int QKVC = 1536;   // 3*HID
constexpr int N_   = 4096;   // 64*64
constexpr int CTXS = 4224;   // per-nc ctxp stride: 4096 ctx + 128 rsum slots

__device__ __forceinline__ u16 f2b(float f) {   // RNE f32->bf16
  union { float f; unsigned u; } v{f};
  unsigned r = v.u + 0x7fff + ((v.u >> 16) & 1);
  return (u16)(r >> 16);
}
__device__ __forceinline__ float b2f(u16 h) {
  union { unsigned u; float f; } v; v.u = ((unsigned)h) << 16; return v.f;
}

// async global->LDS, 16B per lane; lds dest = wave-uniform base + lane*16B
__device__ __forceinline__ void gld_lds16(const u16* g, u16* l) {
  __builtin_amdgcn_global_load_lds(
      (const __attribute__((address_space(1))) unsigned*)g,
      (__attribute__((address_space(3))) unsigned*)l, 16, 0, 0);
}

// ---------------- weights -> bf16 (once per call) ----------------
__global__ void k_cvtw(const float* __restrict__ wq, const float* __restrict__ wo,
                       u16* __restrict__ wqb, u16* __restrict__ wob) {
  int i = blockIdx.x * 256 + threadIdx.x;
  for (int idx = i; idx < QKVC * C_; idx += gridDim.x * 256) wqb[idx] = f2b(wq[idx]);
  for (int idx = i; idx < C_ * HID; idx += gridDim.x * 256) wob[idx] = f2b(wo[idx]);
}

// ---------------- rmsnorm1 + transpose to bf16 [g][n][c] ----------------
__global__ __launch_bounds__(256) void k_rms1(const float* __restrict__ x,
                                              const float* __restrict__ g1,
                                              u16* __restrict__ xbT) {
  int g = blockIdx.y;
  int n = blockIdx.x * 64 + (threadIdx.x & 63);
  int ch = threadIdx.x >> 6;                   // c-quarter 0..3
  __shared__ float ssp[4][64];
  __shared__ float invs[64];
  const float* xp = x + (size_t)g * C_ * N_ + n;
  float ss = 0.f;
  #pragma unroll 16
  for (int c = ch * 64; c < ch * 64 + 64; ++c) {
    float v = xp[(size_t)c * N_];
    ss += v * v;
  }
  ssp[ch][n & 63] = ss;
  __syncthreads();
  if (threadIdx.x < 64) {
    float tot = (ssp[0][threadIdx.x] + ssp[1][threadIdx.x]) +
                (ssp[2][threadIdx.x] + ssp[3][threadIdx.x]);
    invs[threadIdx.x] = 16.0f / fmaxf(sqrtf(tot), 1e-12f);
  }
  __syncthreads();
  float inv = invs[n & 63];
  u16* op = xbT + ((size_t)g * N_ + n) * C_;
  #pragma unroll 2
  for (int c0 = ch * 64; c0 < ch * 64 + 64; c0 += 8) {
    union { bf16x8 v; u16 u[8]; } pk;
    #pragma unroll
    for (int j = 0; j < 8; ++j) pk.u[j] = f2b(xp[(size_t)(c0 + j) * N_] * inv * g1[c0 + j]);
    *(bf16x8*)(op + c0) = pk.v;
  }
}

// ---------------- fused KV-GEMM + exp + PV-accumulate, BK=64 ----------------
__global__ __launch_bounds__(256) void k_kvctx(const u16* __restrict__ Wb,
                                               const u16* __restrict__ XT,
                                               float* __restrict__ ctxp) {
  __shared__ __align__(16) u16 smem[16384];    // 32 KB
  u16* Ws = smem;
  u16* Xs = smem + 8192;
  u16* Pl = smem;
  u16* Vl = smem + 8192;

  int cpx = gridDim.x >> 3;                    // nwg = 64*G, %8==0
  int bid = blockIdx.x;
  int L = (bid & 7) * cpx + (bid >> 3);
  int h = L & 7, nc = (L >> 3) & 7, g = L >> 6;
  int t = threadIdx.x, wave = t >> 6, lane = t & 63;
  int wm = wave >> 1, wn = wave & 1;
  int kg = lane >> 4, lr = lane & 15;

  const u16* WK = Wb + (size_t)(HID + h * DH) * C_;
  const u16* WV = Wb + (size_t)(2 * HID + h * DH) * C_;
  const u16* Xg = XT + ((size_t)g * N_ + nc * 512) * C_;

  int rl8 = lane >> 3;
  int cs8 = (lane & 7) ^ rl8;
  const u16* Wsrc = (wave < 2) ? WK : WV;

  f32x4 acc2[4];
  #pragma unroll
  for (int nf = 0; nf < 4; ++nf) acc2[nf] = (f32x4)0.f;
  float rs[4] = {0.f, 0.f, 0.f, 0.f};

  for (int it = 0; it < 4; ++it) {
    f32x4 acc[4][4];
    #pragma unroll
    for (int i = 0; i < 4; ++i)
      #pragma unroll
      for (int j = 0; j < 4; ++j) acc[i][j] = (f32x4)0.f;

    for (int k0 = 0; k0 < C_; k0 += 64) {
      #pragma unroll
      for (int q = 0; q < 4; ++q) {
        int rb = wave * 32 + q * 8;
        int rw = (rb & 63) + rl8;
        int rx = it * 128 + rb + rl8;
        gld_lds16(Wsrc + (size_t)rw * C_ + k0 + cs8 * 8, Ws + rb * 64);
        gld_lds16(Xg + (size_t)rx * C_ + k0 + cs8 * 8, Xs + rb * 64);
      }
      __syncthreads();
      #pragma unroll
      for (int ks = 0; ks < 2; ++ks) {
        int ch = ks * 4 + kg;
        bf16x8 a[4], bv[4];
        #pragma unroll
        for (int mf = 0; mf < 4; ++mf) {
          int r = wm * 64 + mf * 16 + lr;
          a[mf] = *(const bf16x8*)(Xs + r * 64 + ((ch ^ (r & 7)) * 8));
        }
        #pragma unroll
        for (int nf = 0; nf < 4; ++nf) {
          int r = wn * 64 + nf * 16 + lr;
          bv[nf] = *(const bf16x8*)(Ws + r * 64 + ((ch ^ (r & 7)) * 8));
        }
        #pragma unroll
        for (int mf = 0; mf < 4; ++mf)
          #pragma unroll
          for (int nf = 0; nf < 4; ++nf)
            acc[mf][nf] = __builtin_amdgcn_mfma_f32_16x16x32_bf16(a[mf], bv[nf], acc[mf][nf], 0, 0, 0);
      }
      __syncthreads();
    }

    if (wn == 0) {
      #pragma unroll
      for (int mf = 0; mf < 4; ++mf) {
        int nb = wm * 64 + mf * 16 + kg * 4;
        int cc = nb >> 3, off = nb & 7;
        #pragma unroll
        for (int nf = 0; nf < 4; ++nf) {
          int d = nf * 16 + lr;
          float e0 = __expf(acc[mf][nf][0]);
          float e1 = __expf(acc[mf][nf][1]);
          float e2 = __expf(acc[mf][nf][2]);
          float e3 = __expf(acc[mf][nf][3]);
          rs[nf] += (e0 + e1) + (e2 + e3);
          union { bf16x4 v; u16 u[4]; } pk;
          pk.u[0] = f2b(e0); pk.u[1] = f2b(e1); pk.u[2] = f2b(e2); pk.u[3] = f2b(e3);
          *(bf16x4*)(Pl + d * 128 + ((cc ^ (d & 15)) * 8) + off) = pk.v;
        }
      }
    } else {
      #pragma unroll
      for (int mf = 0; mf < 4; ++mf) {
        int nb = wm * 64 + mf * 16 + kg * 4;
        int cc = nb >> 3, off = nb & 7;
        #pragma unroll
        for (int nf = 0; nf < 4; ++nf) {
          int e = nf * 16 + lr;
          union { bf16x4 v; u16 u[4]; } pk;
          pk.u[0] = f2b(acc[mf][nf][0]); pk.u[1] = f2b(acc[mf][nf][1]);
          pk.u[2] = f2b(acc[mf][nf][2]); pk.u[3] = f2b(acc[mf][nf][3]);
          *(bf16x4*)(Vl + e * 128 + ((cc ^ (e & 15)) * 8) + off) = pk.v;
        }
      }
    }
    __syncthreads();

    #pragma unroll
    for (int k = 0; k < 4; ++k) {
      int c = k * 4 + kg;
      bf16x8 af = *(const bf16x8*)(Pl + (wave * 16 + lr) * 128 + ((c ^ lr) * 8));
      #pragma unroll
      for (int nf = 0; nf < 4; ++nf) {
        bf16x8 bfv = *(const bf16x8*)(Vl + (nf * 16 + lr) * 128 + ((c ^ lr) * 8));
        acc2[nf] = __builtin_amdgcn_mfma_f32_16x16x32_bf16(af, bfv, acc2[nf], 0, 0, 0);
      }
    }
    __syncthreads();
  }

  float* cgp = ctxp + ((size_t)(g * NH + h) * 8 + nc) * CTXS;
  #pragma unroll
  for (int nf = 0; nf < 4; ++nf)
    #pragma unroll
    for (int j = 0; j < 4; ++j) {
      int d = wave * 16 + kg * 4 + j;
      int e = nf * 16 + lr;
      cgp[d * 64 + e] = acc2[nf][j];
    }
  if (wn == 0) {
    #pragma unroll
    for (int nf = 0; nf < 4; ++nf) {
      rs[nf] += __shfl_xor(rs[nf], 16);
      rs[nf] += __shfl_xor(rs[nf], 32);
    }
    if (lane < 16) {
      #pragma unroll
      for (int nf = 0; nf < 4; ++nf)
        cgp[4096 + wm * 64 + nf * 16 + lane] = rs[nf];
    }
  }
}

// ---------------- ctx finalize + Wo2 = Wo_h @ ctx_h^T : wo2[g][c][h*64+d] bf16 ----------------
__global__ __launch_bounds__(256) void k_cwo(const float* __restrict__ ctxp,
                                             const float* __restrict__ memkv,
                                             const u16* __restrict__ Wo,
                                             u16* __restrict__ wo2) {
  int g = blockIdx.y, h = blockIdx.x;
  int t = threadIdx.x, wave = t >> 6, lane = t & 63;
  int kg = lane >> 4, lr = lane & 15;
  int rl8 = lane >> 3, cs8 = (lane & 7) ^ rl8;
  __shared__ float emk[DH * NMEM];
  __shared__ float sd[DH];
  __shared__ __align__(16) u16 Cl[64 * 64];    // ctx[d][e] bf16, swizzled (8 KB)
  __shared__ __align__(16) u16 As2[256 * 64];  // Wo slice rows c x 64 e (32 KB)

  const float* mk = memkv + (size_t)h * DH * NMEM;
  const float* mv = memkv + (size_t)(NH + h) * DH * NMEM;
  const float* cp = ctxp + (size_t)(g * NH + h) * 8 * CTXS;
  emk[t] = __expf(mk[t]);
  __syncthreads();
  if (t < DH) {
    float s = 0.f;
    #pragma unroll
    for (int p = 0; p < 8; ++p)
      s += cp[p * CTXS + 4096 + t] + cp[p * CTXS + 4160 + t];
    #pragma unroll
    for (int j = 0; j < NMEM; ++j) s += emk[t * 4 + j];
    sd[t] = s;
  }
  #pragma unroll
  for (int q = 0; q < 8; ++q) {
    int rb = wave * 64 + q * 8;
    gld_lds16(Wo + (size_t)(rb + rl8) * HID + h * DH + cs8 * 8, As2 + rb * 64);
  }
  __syncthreads();
  #pragma unroll
  for (int i = 0; i < 16; ++i) {
    int idx = t + 256 * i;
    int d = idx >> 6, e = idx & 63;
    float v = 0.f;
    #pragma unroll
    for (int p = 0; p < 8; ++p) v += cp[p * CTXS + idx];
    #pragma unroll
    for (int j = 0; j < NMEM; ++j) v += emk[d * 4 + j] * mv[e * 4 + j];
    Cl[d * 64 + (((e >> 3) ^ (d & 7)) * 8) + (e & 7)] = f2b(v / sd[d]);
  }
  __syncthreads();
  f32x4 acc[4][4];
  #pragma unroll
  for (int i = 0; i < 4; ++i)
    #pragma unroll
    for (int j = 0; j < 4; ++j) acc[i][j] = (f32x4)0.f;
  #pragma unroll
  for (int ks = 0; ks < 2; ++ks) {
    int ch = ks * 4 + kg;
    bf16x8 a[4], b[4];
    #pragma unroll
    for (int mf = 0; mf < 4; ++mf) {
      int r = wave * 64 + mf * 16 + lr;
      a[mf] = *(const bf16x8*)(As2 + r * 64 + ((ch ^ (r & 7)) * 8));
    }
    #pragma unroll
    for (int nf = 0; nf < 4; ++nf) {
      int rd = nf * 16 + lr;
      b[nf] = *(const bf16x8*)(Cl + rd * 64 + ((ch ^ (rd & 7)) * 8));
    }
    #pragma unroll
    for (int mf = 0; mf < 4; ++mf)
      #pragma unroll
      for (int nf = 0; nf < 4; ++nf)
        acc[mf][nf] = __builtin_amdgcn_mfma_f32_16x16x32_bf16(a[mf], b[nf], acc[mf][nf], 0, 0, 0);
  }
  u16* og = wo2 + (size_t)g * 256 * 512;
  #pragma unroll
  for (int mf = 0; mf < 4; ++mf)
    #pragma unroll
    for (int nf = 0; nf < 4; ++nf)
      #pragma unroll
      for (int j = 0; j < 4; ++j) {
        int c = wave * 64 + mf * 16 + kg * 4 + j;
        int dd = nf * 16 + lr;
        og[(size_t)c * 512 + h * DH + dd] = f2b(acc[mf][nf][j]);
      }
}

// ---------------- fused Q-GEMM + q-softmax + out-proj + rmsnorm2 ----------------
// 1024 threads, 128-n tile, 16 waves. Phase A: wave (h=wave&7, nh2=wave>>3)
// computes head h x 64-n half -> acc[4][4] (64 regs, no spill at 128-VGPR tier).
// Phase B: wave-local softmax, pq packed. Phase C: wave (wc, nh2) = 32c x 64n.
__global__ __launch_bounds__(1024) void k_qout(const u16* __restrict__ Wq,
                                               const u16* __restrict__ XT,
                                               const u16* __restrict__ Wo2,
                                               const float* __restrict__ bias,
                                               const float* __restrict__ g2,
                                               float* __restrict__ out) {
  __shared__ __align__(16) u16 smem[49152];    // 96 KB
  u16* R0 = smem;            // 32 KB: Wq-stage (512x32) / Wo2-stage (256x64) / part
  u16* R1 = smem + 16384;    // 64 KB: X-tile [128 n][256 c] / Ql half [128 n][256 o]

  int cpx = gridDim.x >> 3;                    // nwg = 32*G, %8==0
  int bid = blockIdx.x;
  int L = (bid & 7) * cpx + (bid >> 3);
  int nc = L & 31, g = L >> 5;
  int t = threadIdx.x, wave = t >> 6, lane = t & 63;
  int kg = lane >> 4, lr = lane & 15;
  int rl4 = lane >> 2, cs4 = (lane & 3) ^ (rl4 & 3);   // 4-chunk rows (64B)
  int rl8 = lane >> 3, cs8 = (lane & 7) ^ rl8;         // 8-chunk rows (128B)
  int hq = wave & 7, nh2 = wave >> 3;          // phase A: head, n-half

  const u16* Xg = XT + ((size_t)g * N_ + nc * 128) * C_;
  const u16* W2g = Wo2 + (size_t)g * 256 * 512;

  // stage X tile once: [128 n][256 c], low-3-chunk swizzle by n&7; wave owns 8 rows
  {
    int xrow_off = lane >> 5;                  // 0..1
    int c32 = lane & 31;
    #pragma unroll
    for (int q = 0; q < 4; ++q) {
      int base = wave * 8 + q * 2;
      int row = base + xrow_off;
      int sw = (c32 & 24) | ((c32 & 7) ^ (row & 7));
      gld_lds16(Xg + (size_t)row * C_ + sw * 8, R1 + base * 256);
    }
  }

  // ---- phase A: Q-GEMM, BK=32, 8 steps; wave = head hq x n-half nh2 ----
  f32x4 acc[4][4];
  #pragma unroll
  for (int i = 0; i < 4; ++i)
    #pragma unroll
    for (int j = 0; j < 4; ++j) acc[i][j] = (f32x4)0.f;

  for (int k0i = 0; k0i < 8; ++k0i) {
    int k0 = k0i * 32;
    #pragma unroll
    for (int q = 0; q < 2; ++q) {              // Wq slice 512 rows x 32 (2 loads/thread)
      int rb = ((wave * 2 + q) & 31) * 16;
      gld_lds16(Wq + (size_t)(rb + rl4) * C_ + k0 + cs4 * 8, R0 + rb * 32);
    }
    __syncthreads();
    bf16x8 a[4], bv[4];
    #pragma unroll
    for (int mf = 0; mf < 4; ++mf) {           // A = Wq rows (o) of head hq
      int r = hq * 64 + mf * 16 + lr;
      a[mf] = *(const bf16x8*)(R0 + r * 32 + ((kg ^ (r & 3)) * 8));
    }
    #pragma unroll
    for (int nf = 0; nf < 4; ++nf) {           // B = X rows (n) of half nh2
      int bn = nh2 * 64 + nf * 16 + lr;
      int c32 = k0i * 4 + kg;
      int sw = (c32 & 24) | ((c32 & 7) ^ (bn & 7));
      bv[nf] = *(const bf16x8*)(R1 + bn * 256 + sw * 8);
    }
    #pragma unroll
    for (int mf = 0; mf < 4; ++mf)
      #pragma unroll
      for (int nf = 0; nf < 4; ++nf)
        acc[mf][nf] = __builtin_amdgcn_mfma_f32_16x16x32_bf16(a[mf], bv[nf], acc[mf][nf], 0, 0, 0);
    __syncthreads();
  }

  // ---- phase B: wave-local softmax over d (64 rows of head hq); pack bf16 pairs ----
  float colsum[4];
  #pragma unroll
  for (int nf = 0; nf < 4; ++nf) {
    float s = 0.f;
    #pragma unroll
    for (int mf = 0; mf < 4; ++mf)
      #pragma unroll
      for (int j = 0; j < 4; ++j) {
        float e = __expf(acc[mf][nf][j]);
        acc[mf][nf][j] = e;
        s += e;
      }
    colsum[nf] = s;
  }
  #pragma unroll
  for (int nf = 0; nf < 4; ++nf) {
    colsum[nf] += __shfl_xor(colsum[nf], 16);
    colsum[nf] += __shfl_xor(colsum[nf], 32);
    colsum[nf] = 0.125f / colsum[nf];
  }
  unsigned pq[4][4][2];                        // packed qsm (32 VGPRs; acc dies)
  #pragma unroll
  for (int nf = 0; nf < 4; ++nf) {
    float invs = colsum[nf];
    #pragma unroll
    for (int mf = 0; mf < 4; ++mf)
      #pragma unroll
      for (int jp = 0; jp < 2; ++jp) {
        u16 lo = f2b(acc[mf][nf][jp * 2] * invs);
        u16 hi = f2b(acc[mf][nf][jp * 2 + 1] * invs);
        pq[mf][nf][jp] = (unsigned)lo | ((unsigned)hi << 16);
      }
  }

  // ---- phase C: out-GEMM in two 256-o halves; wave = (wc=wave&7) x nh2 ----
  int wc = wave & 7;
  f32x4 acc2[2][4];
  #pragma unroll
  for (int i = 0; i < 2; ++i)
    #pragma unroll
    for (int j = 0; j < 4; ++j) acc2[i][j] = (f32x4)0.f;

  #pragma unroll
  for (int half = 0; half < 2; ++half) {
    if ((hq >> 2) == half) {                   // heads of this half write their Ql
      #pragma unroll
      for (int nf = 0; nf < 4; ++nf) {
        int n = nh2 * 64 + nf * 16 + lr;
        #pragma unroll
        for (int mf = 0; mf < 4; ++mf)
          #pragma unroll
          for (int jp = 0; jp < 2; ++jp) {
            int oc = (hq & 3) * 64 + mf * 16 + kg * 4 + jp * 2;
            int c8 = oc >> 3;
            int sw = (c8 & 24) | ((c8 & 7) ^ (n & 7));
            *(unsigned*)(R1 + n * 256 + sw * 8 + (oc & 7)) = pq[mf][nf][jp];
          }
      }
    }
    __syncthreads();
    for (int k0l = 0; k0l < 4; ++k0l) {
      int cb = half * 256 + k0l * 64;
      #pragma unroll
      for (int q = 0; q < 2; ++q) {            // Wo2 slice 256 rows x 64 (2 loads/thread)
        int rb = ((wave * 2 + q) & 31) * 8;
        gld_lds16(W2g + (size_t)(rb + rl8) * 512 + cb + cs8 * 8, R0 + rb * 64);
      }
      __syncthreads();
      #pragma unroll
      for (int ks = 0; ks < 2; ++ks) {
        int ch = ks * 4 + kg;
        bf16x8 a2[2], b2[4];
        #pragma unroll
        for (int mf = 0; mf < 2; ++mf) {       // A = Wo2 rows (c), 32 per wave
          int r = wc * 32 + mf * 16 + lr;
          a2[mf] = *(const bf16x8*)(R0 + r * 64 + ((ch ^ (r & 7)) * 8));
        }
        #pragma unroll
        for (int nf = 0; nf < 4; ++nf) {       // B = Ql rows (n) of half nh2
          int bn = nh2 * 64 + nf * 16 + lr;
          int c8 = k0l * 8 + ks * 4 + kg;
          int sw = (c8 & 24) | ((c8 & 7) ^ (bn & 7));
          b2[nf] = *(const bf16x8*)(R1 + bn * 256 + sw * 8);
        }
        #pragma unroll
        for (int mf = 0; mf < 2; ++mf)
          #pragma unroll
          for (int nf = 0; nf < 4; ++nf)
            acc2[mf][nf] = __builtin_amdgcn_mfma_f32_16x16x32_bf16(a2[mf], b2[nf], acc2[mf][nf], 0, 0, 0);
      }
      __syncthreads();
    }
  }

  // ---- epilogue: bias + rmsnorm over c (256 rows) + store ----
  float colsq[4] = {0.f, 0.f, 0.f, 0.f};
  #pragma unroll
  for (int mf = 0; mf < 2; ++mf)
    #pragma unroll
    for (int j = 0; j < 4; ++j) {
      int c = wc * 32 + mf * 16 + kg * 4 + j;
      float bs = bias[c];
      #pragma unroll
      for (int nf = 0; nf < 4; ++nf) {
        float v = acc2[mf][nf][j] + bs;
        acc2[mf][nf][j] = v;
        colsq[nf] += v * v;
      }
    }
  #pragma unroll
  for (int nf = 0; nf < 4; ++nf) {
    colsq[nf] += __shfl_xor(colsq[nf], 16);
    colsq[nf] += __shfl_xor(colsq[nf], 32);
  }
  float* part = (float*)R0;                    // 16 x 64 f32 = 4 KB
  if (kg == 0) {
    #pragma unroll
    for (int nf = 0; nf < 4; ++nf) part[wave * 64 + nf * 16 + lr] = colsq[nf];
  }
  __syncthreads();
  float* og = out + (size_t)g * C_ * N_ + nc * 128;
  #pragma unroll
  for (int nf = 0; nf < 4; ++nf) {
    int cl_ = nf * 16 + lr;                    // column local to nh2 group
    float tot = 0.f;
    #pragma unroll
    for (int w = 0; w < 8; ++w) tot += part[(nh2 * 8 + w) * 64 + cl_];
    float invn = 16.0f / fmaxf(sqrtf(tot), 1e-12f);
    int col = nh2 * 64 + cl_;
    #pragma unroll
    for (int mf = 0; mf < 2; ++mf)
      #pragma unroll
      for (int j = 0; j < 4; ++j) {
        int c = wc * 32 + mf * 16 + kg * 4 + j;
        og[(size_t)c * N_ + col] = acc2[mf][nf][j] * invn * g2[c];
      }
  }
}

extern "C" void kernel_launch(void* const* d_in, const int* in_sizes, int n_in,
                              void* d_out, int out_size, void* d_ws, size_t ws_size,
                              hipStream_t stream) {
  (void)in_sizes; (void)n_in; (void)out_size;
  const float* x      = (const float*)d_in[0];
  const float* gain1  = (const float*)d_in[1];
  const float* w_qkv  = (const float*)d_in[2];
  const float* mem_kv = (const float*)d_in[3];
  const float* w_out  = (const float*)d_in[4];
  const float* b_out  = (const float*)d_in[5];
  const float* gain2  = (const float*)d_in[6];
  float* out = (float*)d_out;

  char* ws = (char*)d_ws;
  u16* wqkvb = (u16*)ws;                         // 786,432 B
  u16* woutb = (u16*)(ws + 786432);              // 262,144 B
  size_t shared_b = 1048576;

  const size_t xbT_b  = (size_t)N_ * C_ * 2;           //  2 MiB
  const size_t ctxp_b = (size_t)NH * 8 * CTXS * 4;     // ~1.03 MiB
  const size_t wo2_b  = (size_t)256 * 512 * 2;         // 256 KiB
  const size_t per_b  = xbT_b + ctxp_b + wo2_b;

  int G = 16;
  while (G > 1 && shared_b + (size_t)G * per_b > ws_size) G >>= 1;

  char* base = ws + shared_b;
  u16*   xbT  = (u16*)base;
  float* ctxp = (float*)(base + (size_t)G * xbT_b);
  u16*   wo2  = (u16*)(base + (size_t)G * (xbT_b + ctxp_b));

  k_cvtw<<<256, 256, 0, stream>>>(w_qkv, w_out, wqkvb, woutb);

  for (int b0 = 0; b0 < B_; b0 += G) {
    const float* xc = x + (size_t)b0 * C_ * N_;
    float*       oc = out + (size_t)b0 * C_ * N_;
    k_rms1  <<<dim3(N_ / 64, G),   256, 0, stream>>>(xc, gain1, xbT);
    k_kvctx <<<dim3(64 * G),       256, 0, stream>>>(wqkvb, xbT, ctxp);
    k_cwo   <<<dim3(NH, G),        256, 0, stream>>>(ctxp, mem_kv, woutb, wo2);
    k_qout  <<<dim3(32 * G),       1024, 0, stream>>>(wqkvb, xbT, wo2, b_out, gain2, oc);
  }
}